// Round 14
// baseline (608.397 us; speedup 1.0000x reference)
//
#include <hip/hip_runtime.h>
#include <hip/hip_bf16.h>
#include <math.h>

// ---- problem constants ----
constexpr int N_    = 4;
constexpr int LQ    = 900;
constexpr int D     = 256;
constexpr int HEADS = 8;
constexpr int DH    = 32;
constexpr int NPTS  = 4;
constexpr int LEN   = 16384;   // 128*128
constexpr int H_    = 128;
constexpr int W_    = 128;
constexpr int DFF   = 1024;
constexpr int NLAYERS = 6;
constexpr int MQ    = N_ * LQ;   // 3600
constexpr int MV    = N_ * LEN;  // 65536
constexpr int MB    = (MQ + 63) / 64;   // 57
constexpr int VBLK  = (D / 128) * (MV / 128);  // 1024 value blocks
constexpr int QBLK  = 2 * MB;                  // 114 qoa blocks
constexpr int BBLK  = 4 * MB;                  // 228 b1 blocks
constexpr int MB128 = (MQ + 127) / 128;        // 29 row-blocks for 128-tile fc

typedef __attribute__((ext_vector_type(8))) short bf16x8;
typedef __attribute__((ext_vector_type(4))) float f32x4;

static __device__ __forceinline__ unsigned short f2bf(float v) {
    __hip_bfloat16 h = __float2bfloat16(v);
    return *(unsigned short*)&h;
}
static __device__ __forceinline__ float bf2f(unsigned short u) {
    __hip_bfloat16 h = *(__hip_bfloat16*)&u;
    return __bfloat162float(h);
}
static __device__ __forceinline__ bf16x8 pack8(const float* a, const float* b4) {
    union { bf16x8 v; unsigned short u[8]; } o;
    o.u[0] = f2bf(a[0]); o.u[1] = f2bf(a[1]); o.u[2] = f2bf(a[2]); o.u[3] = f2bf(a[3]);
    o.u[4] = f2bf(b4[0]); o.u[5] = f2bf(b4[1]); o.u[6] = f2bf(b4[2]); o.u[7] = f2bf(b4[3]);
    return o.v;
}

// async global->LDS, 16 B per lane (LDS dest wave-uniform base + lane*16)
static __device__ __forceinline__ void gload_lds16(const void* gaddr, void* laddr) {
    __builtin_amdgcn_global_load_lds(
        (const __attribute__((address_space(1))) unsigned int*)gaddr,
        (__attribute__((address_space(3))) unsigned int*)laddr,
        16, 0, 0);
}

// =====================================================================
// fp32 -> bf16 conversion (contiguous), n8 = count/8
// =====================================================================
__global__ __launch_bounds__(256) void cvt_bf16_kernel(
    const float* __restrict__ in, unsigned short* __restrict__ out, int n8)
{
    int i = blockIdx.x * 256 + threadIdx.x;
    if (i >= n8) return;
    float4 a = ((const float4*)in)[i * 2];
    float4 b = ((const float4*)in)[i * 2 + 1];
    float af[4] = {a.x, a.y, a.z, a.w}, bff[4] = {b.x, b.y, b.z, b.w};
    *(bf16x8*)(out + (size_t)i * 8) = pack8(af, bff);
}

// =====================================================================
// 4x D x D weight transpose+cvt in one dispatch (Wv, Wout, Wb1, Wb2)
// =====================================================================
__global__ __launch_bounds__(256) void wt_cvt4_kernel(
    const float* __restrict__ W0, const float* __restrict__ W1,
    const float* __restrict__ W2, const float* __restrict__ W3,
    unsigned short* __restrict__ T0, unsigned short* __restrict__ T1,
    unsigned short* __restrict__ T2, unsigned short* __restrict__ T3)
{
    int i = blockIdx.x * 256 + threadIdx.x;
    if (i >= NLAYERS * D * D) return;
    int k = i & (D - 1);
    int n = (i >> 8) & (D - 1);
    int l = i >> 16;
    size_t si = (size_t)l * D * D + (size_t)k * D + n;
    T0[i] = f2bf(W0[si]);
    T1[i] = f2bf(W1[si]);
    T2[i] = f2bf(W2[si]);
    T3[i] = f2bf(W3[si]);
}

// =====================================================================
// generic weight transpose+cvt: W (L,K,N) fp32 -> WT (L,Npad,K) bf16
// =====================================================================
__global__ __launch_bounds__(256) void wt_cvt_kernel(
    const float* __restrict__ W, unsigned short* __restrict__ WT,
    int K, int Nr, int Npad, int total)
{
    int i = blockIdx.x * 256 + threadIdx.x;
    if (i >= total) return;
    int k = i % K;
    int n = (i / K) % Npad;
    int l = i / (K * Npad);
    WT[i] = (n < Nr) ? f2bf(W[((size_t)l * K + k) * Nr + n]) : (unsigned short)0;
}

// =====================================================================
// WoaT: rows 0..63 = Wo^T (N=64), rows 64..95 = Wa^T (N=32), 96..127 = 0
// =====================================================================
__global__ __launch_bounds__(256) void woat_kernel(
    const float* __restrict__ Wo, const float* __restrict__ Wa,
    unsigned short* __restrict__ WoaT)
{
    int i = blockIdx.x * 256 + threadIdx.x;
    if (i >= NLAYERS * 128 * D) return;
    int k = i % D;
    int n = (i / D) & 127;
    int l = i / (D * 128);
    float v = 0.f;
    if (n < 64)      v = Wo[((size_t)l * D + k) * 64 + n];
    else if (n < 96) v = Wa[((size_t)l * D + k) * 32 + (n - 64)];
    WoaT[i] = f2bf(v);
}

__global__ __launch_bounds__(256) void bias_concat_kernel(
    const float* __restrict__ bo, const float* __restrict__ ba, float* __restrict__ boa)
{
    int i = blockIdx.x * 256 + threadIdx.x;
    if (i >= NLAYERS * 128) return;
    int n = i & 127;
    int l = i >> 7;
    float v = 0.f;
    if (n < 64)      v = bo[l * 64 + n];
    else if (n < 96) v = ba[l * 32 + (n - 64)];
    boa[i] = v;
}

// =====================================================================
// 3-way fused dispatch (r12-validated):
//   [0, VBLK):           value GEMM layer l+1 (128x128, XCD pairing)
//   [VBLK, VBLK+QBLK):   qoa GEMM layer l+1 (64x64, fused add)
//   [VBLK+QBLK, +BBLK):  b1 GEMM layer l (64x64, bf16 A, relu, bf16 out)
// =====================================================================
template<bool HAS_B1>
__global__ __launch_bounds__(256) void fused_vq_kernel(
    const unsigned short* __restrict__ A, const unsigned short* __restrict__ Bt,
    const float* __restrict__ bias, const unsigned char* __restrict__ mask,
    unsigned short* __restrict__ C,
    const float* __restrict__ Aq, const float* __restrict__ A2q,
    const unsigned short* __restrict__ Btq, const float* __restrict__ biasq,
    float* __restrict__ Cq,
    const unsigned short* __restrict__ Ab1, const unsigned short* __restrict__ Btb1,
    const float* __restrict__ biasb1, unsigned short* __restrict__ Cb1)
{
    __shared__ unsigned short Asm[128 * 64];
    __shared__ unsigned short Bsm[128 * 64];

    const int bid  = blockIdx.x;
    const int tid  = threadIdx.x;
    const int wave = tid >> 6;
    const int lane = tid & 63;
    const int lg   = lane >> 4;
    const int lr   = lane & 15;

    if (bid < VBLK) {
        const int y  = (bid >> 4) * 8 + (bid & 7);
        const int x  = (bid >> 3) & 1;
        const int m0 = y * 128;
        const int n0 = x * 128;
        const int wr = wave >> 1;
        const int wc = wave & 1;

        f32x4 acc[4][4];
#pragma unroll
        for (int i = 0; i < 4; ++i)
#pragma unroll
            for (int j = 0; j < 4; ++j) acc[i][j] = (f32x4){0.f, 0.f, 0.f, 0.f};

        for (int k0 = 0; k0 < D; k0 += 64) {
#pragma unroll
            for (int it = 0; it < 4; ++it) {
                int c   = tid + it * 256;
                int row = c >> 3;
                int kch = (c & 7) ^ (row & 7);
                unsigned ldsoff = (unsigned)(it * 256 + wave * 64) * 16;
                gload_lds16(A  + (size_t)(m0 + row) * D + k0 + kch * 8, (char*)Asm + ldsoff);
                gload_lds16(Bt + (size_t)(n0 + row) * D + k0 + kch * 8, (char*)Bsm + ldsoff);
            }
            __syncthreads();

            bf16x8 af[4][2], bfr[4][2];
#pragma unroll
            for (int i = 0; i < 4; ++i) {
#pragma unroll
                for (int kk = 0; kk < 2; ++kk) {
                    int arow = wr * 64 + i * 16 + lr;
                    af[i][kk]  = *(const bf16x8*)((char*)Asm + arow * 128 + 16 * ((kk * 4 + lg) ^ (arow & 7)));
                    int brow = wc * 64 + i * 16 + lr;
                    bfr[i][kk] = *(const bf16x8*)((char*)Bsm + brow * 128 + 16 * ((kk * 4 + lg) ^ (brow & 7)));
                }
            }
#pragma unroll
            for (int kk = 0; kk < 2; ++kk)
#pragma unroll
                for (int i = 0; i < 4; ++i)
#pragma unroll
                    for (int j = 0; j < 4; ++j)
                        acc[i][j] = __builtin_amdgcn_mfma_f32_16x16x32_bf16(
                            af[i][kk], bfr[j][kk], acc[i][j], 0, 0, 0);
            __syncthreads();
        }

#pragma unroll
        for (int i = 0; i < 4; ++i) {
            int mbase = m0 + wr * 64 + i * 16 + lg * 4;
#pragma unroll
            for (int j = 0; j < 4; ++j) {
                int n = n0 + wc * 64 + j * 16 + lr;
                float bn = bias[n];
#pragma unroll
                for (int r = 0; r < 4; ++r) {
                    int m = mbase + r;
                    float v = acc[i][j][r] + bn;
                    if (mask[m]) v = 0.f;
                    C[(size_t)m * D + n] = f2bf(v);
                }
            }
        }
    } else if (bid < VBLK + QBLK) {
        const int qb = bid - VBLK;
        const int n0 = (qb & 1) * 64;
        const int m0 = (qb >> 1) * 64;
        const int wr = wave >> 1;
        const int wc = wave & 1;

        f32x4 acc[2][2];
#pragma unroll
        for (int i = 0; i < 2; ++i)
#pragma unroll
            for (int j = 0; j < 2; ++j) acc[i][j] = (f32x4){0.f, 0.f, 0.f, 0.f};

        for (int k0 = 0; k0 < D; k0 += 64) {
#pragma unroll
            for (int it = 0; it < 2; ++it) {
                int c   = tid + it * 256;
                int row = c >> 3;
                int kc  = c & 7;
                int kch = kc ^ (row & 7);
                unsigned ldsoff = (unsigned)(it * 256 + wave * 64) * 16;
                gload_lds16(Btq + (size_t)(n0 + row) * D + k0 + kch * 8, (char*)Bsm + ldsoff);
                int gm = m0 + row;
                bf16x8 v = (bf16x8){0,0,0,0,0,0,0,0};
                if (gm < MQ) {
                    const float* ap = Aq  + (size_t)gm * D + k0 + kc * 8;
                    const float* qp = A2q + (size_t)gm * D + k0 + kc * 8;
                    float4 a = *(const float4*)ap;
                    float4 b = *(const float4*)(ap + 4);
                    float4 qa = *(const float4*)qp;
                    float4 qb4 = *(const float4*)(qp + 4);
                    a.x += qa.x; a.y += qa.y; a.z += qa.z; a.w += qa.w;
                    b.x += qb4.x; b.y += qb4.y; b.z += qb4.z; b.w += qb4.w;
                    float af_[4] = {a.x, a.y, a.z, a.w}, bf_[4] = {b.x, b.y, b.z, b.w};
                    v = pack8(af_, bf_);
                }
                *(bf16x8*)((char*)Asm + row * 128 + 16 * (kc ^ (row & 7))) = v;
            }
            __syncthreads();

            bf16x8 af[2][2], bfr[2][2];
#pragma unroll
            for (int i = 0; i < 2; ++i) {
#pragma unroll
                for (int kk = 0; kk < 2; ++kk) {
                    int arow = wr * 32 + i * 16 + lr;
                    af[i][kk]  = *(const bf16x8*)((char*)Asm + arow * 128 + 16 * ((kk * 4 + lg) ^ (arow & 7)));
                    int brow = wc * 32 + i * 16 + lr;
                    bfr[i][kk] = *(const bf16x8*)((char*)Bsm + brow * 128 + 16 * ((kk * 4 + lg) ^ (brow & 7)));
                }
            }
#pragma unroll
            for (int kk = 0; kk < 2; ++kk)
#pragma unroll
                for (int i = 0; i < 2; ++i)
#pragma unroll
                    for (int j = 0; j < 2; ++j)
                        acc[i][j] = __builtin_amdgcn_mfma_f32_16x16x32_bf16(
                            af[i][kk], bfr[j][kk], acc[i][j], 0, 0, 0);
            __syncthreads();
        }

#pragma unroll
        for (int i = 0; i < 2; ++i) {
            int mbase = m0 + wr * 32 + i * 16 + lg * 4;
#pragma unroll
            for (int j = 0; j < 2; ++j) {
                int n = n0 + wc * 32 + j * 16 + lr;
                if (n >= 96) continue;
                float bn = biasq[n];
#pragma unroll
                for (int r = 0; r < 4; ++r) {
                    int m = mbase + r;
                    if (m >= MQ) continue;
                    Cq[(size_t)m * 96 + n] = acc[i][j][r] + bn;
                }
            }
        }
    } else if (HAS_B1) {
        const int bb = bid - VBLK - QBLK;
        const int n0 = (bb & 3) * 64;
        const int m0 = (bb >> 2) * 64;
        const int wr = wave >> 1;
        const int wc = wave & 1;

        f32x4 acc[2][2];
#pragma unroll
        for (int i = 0; i < 2; ++i)
#pragma unroll
            for (int j = 0; j < 2; ++j) acc[i][j] = (f32x4){0.f, 0.f, 0.f, 0.f};

        for (int k0 = 0; k0 < D; k0 += 64) {
#pragma unroll
            for (int it = 0; it < 2; ++it) {
                int c   = tid + it * 256;
                int row = c >> 3;
                int kch = (c & 7) ^ (row & 7);
                unsigned ldsoff = (unsigned)(it * 256 + wave * 64) * 16;
                gload_lds16(Btb1 + (size_t)(n0 + row) * D + k0 + kch * 8, (char*)Bsm + ldsoff);
                gload_lds16(Ab1  + (size_t)(m0 + row) * D + k0 + kch * 8, (char*)Asm + ldsoff);
            }
            __syncthreads();

            bf16x8 af[2][2], bfr[2][2];
#pragma unroll
            for (int i = 0; i < 2; ++i) {
#pragma unroll
                for (int kk = 0; kk < 2; ++kk) {
                    int arow = wr * 32 + i * 16 + lr;
                    af[i][kk]  = *(const bf16x8*)((char*)Asm + arow * 128 + 16 * ((kk * 4 + lg) ^ (arow & 7)));
                    int brow = wc * 32 + i * 16 + lr;
                    bfr[i][kk] = *(const bf16x8*)((char*)Bsm + brow * 128 + 16 * ((kk * 4 + lg) ^ (brow & 7)));
                }
            }
#pragma unroll
            for (int kk = 0; kk < 2; ++kk)
#pragma unroll
                for (int i = 0; i < 2; ++i)
#pragma unroll
                    for (int j = 0; j < 2; ++j)
                        acc[i][j] = __builtin_amdgcn_mfma_f32_16x16x32_bf16(
                            af[i][kk], bfr[j][kk], acc[i][j], 0, 0, 0);
            __syncthreads();
        }

#pragma unroll
        for (int i = 0; i < 2; ++i) {
            int mbase = m0 + wr * 32 + i * 16 + lg * 4;
#pragma unroll
            for (int j = 0; j < 2; ++j) {
                int n = n0 + wc * 32 + j * 16 + lr;
#pragma unroll
                for (int r = 0; r < 4; ++r) {
                    int m = mbase + r;
                    if (m >= MQ) continue;
                    float v = fmaxf(acc[i][j][r] + biasb1[n], 0.f);
                    Cb1[(size_t)m * D + n] = f2bf(v);
                }
            }
        }
    }
}

// =====================================================================
// fc GEMM, 128x128 tile: C[MQ,DFF] = relu(x1h @ WfcT^T + bfc) -> bf16.
// A bf16 (gload_lds), tail rows (m>=MQ) stage adjacent-ws garbage (in-bounds,
// discarded by epilogue guard). grid (DFF/128, MB128) = (8, 29).
// =====================================================================
__global__ __launch_bounds__(256) void gemm_fc_mfma(
    const unsigned short* __restrict__ A, const unsigned short* __restrict__ Bt,
    const float* __restrict__ bias, unsigned short* __restrict__ C)
{
    __shared__ unsigned short Asm[128 * 64];
    __shared__ unsigned short Bsm[128 * 64];

    const int tid  = threadIdx.x;
    const int m0   = blockIdx.y * 128;
    const int n0   = blockIdx.x * 128;
    const int wave = tid >> 6;
    const int lane = tid & 63;
    const int wr   = wave >> 1;
    const int wc   = wave & 1;
    const int lg   = lane >> 4;
    const int lr   = lane & 15;

    f32x4 acc[4][4];
#pragma unroll
    for (int i = 0; i < 4; ++i)
#pragma unroll
        for (int j = 0; j < 4; ++j) acc[i][j] = (f32x4){0.f, 0.f, 0.f, 0.f};

    for (int k0 = 0; k0 < D; k0 += 64) {
#pragma unroll
        for (int it = 0; it < 4; ++it) {
            int c   = tid + it * 256;
            int row = c >> 3;
            int kch = (c & 7) ^ (row & 7);
            unsigned ldsoff = (unsigned)(it * 256 + wave * 64) * 16;
            gload_lds16(A  + (size_t)(m0 + row) * D + k0 + kch * 8, (char*)Asm + ldsoff);
            gload_lds16(Bt + (size_t)(n0 + row) * D + k0 + kch * 8, (char*)Bsm + ldsoff);
        }
        __syncthreads();

        bf16x8 af[4][2], bfr[4][2];
#pragma unroll
        for (int i = 0; i < 4; ++i) {
#pragma unroll
            for (int kk = 0; kk < 2; ++kk) {
                int arow = wr * 64 + i * 16 + lr;
                af[i][kk]  = *(const bf16x8*)((char*)Asm + arow * 128 + 16 * ((kk * 4 + lg) ^ (arow & 7)));
                int brow = wc * 64 + i * 16 + lr;
                bfr[i][kk] = *(const bf16x8*)((char*)Bsm + brow * 128 + 16 * ((kk * 4 + lg) ^ (brow & 7)));
            }
        }
#pragma unroll
        for (int kk = 0; kk < 2; ++kk)
#pragma unroll
            for (int i = 0; i < 4; ++i)
#pragma unroll
                for (int j = 0; j < 4; ++j)
                    acc[i][j] = __builtin_amdgcn_mfma_f32_16x16x32_bf16(
                        af[i][kk], bfr[j][kk], acc[i][j], 0, 0, 0);
        __syncthreads();
    }

#pragma unroll
    for (int i = 0; i < 4; ++i) {
        int mbase = m0 + wr * 64 + i * 16 + lg * 4;
#pragma unroll
        for (int j = 0; j < 4; ++j) {
            int n = n0 + wc * 64 + j * 16 + lr;
            float bn = bias[n];
#pragma unroll
            for (int r = 0; r < 4; ++r) {
                int m = mbase + r;
                if (m >= MQ) continue;
                float v = fmaxf(acc[i][j][r] + bn, 0.f);
                C[(size_t)m * DFF + n] = f2bf(v);
            }
        }
    }
}

// =====================================================================
// MFMA query GEMM: C[M,Nreal] = A[M,K] @ Bt^T + bias (+relu). (r10-validated)
// =====================================================================
template<bool ABF16, bool RELU, bool OUTBF16>
__global__ __launch_bounds__(256) void gemm_q_mfma(
    const void* __restrict__ Av,
    const unsigned short* __restrict__ Bt, const float* __restrict__ bias,
    void* __restrict__ Cv, int M, int Nreal, int K)
{
    __shared__ unsigned short Asm[64 * 64];
    __shared__ unsigned short Bsm[64 * 64];

    const int tid  = threadIdx.x;
    const int m0   = blockIdx.y * 64;
    const int n0   = blockIdx.x * 64;
    const int wave = tid >> 6;
    const int lane = tid & 63;
    const int wr   = wave >> 1;
    const int wc   = wave & 1;
    const int lg   = lane >> 4;
    const int lr   = lane & 15;

    f32x4 acc[2][2];
#pragma unroll
    for (int i = 0; i < 2; ++i)
#pragma unroll
        for (int j = 0; j < 2; ++j) acc[i][j] = (f32x4){0.f, 0.f, 0.f, 0.f};

    for (int k0 = 0; k0 < K; k0 += 64) {
#pragma unroll
        for (int it = 0; it < 2; ++it) {
            int c   = tid + it * 256;
            int row = c >> 3;
            int kch = (c & 7) ^ (row & 7);
            unsigned ldsoff = (unsigned)(it * 256 + wave * 64) * 16;
            gload_lds16(Bt + (size_t)(n0 + row) * K + k0 + kch * 8, (char*)Bsm + ldsoff);
            if (ABF16) {
                gload_lds16((const unsigned short*)Av + (size_t)(m0 + row) * K + k0 + kch * 8,
                            (char*)Asm + ldsoff);
            } else {
                int kc = c & 7;
                int gm = m0 + row;
                bf16x8 v = (bf16x8){0,0,0,0,0,0,0,0};
                if (gm < M) {
                    const float* ap = (const float*)Av + (size_t)gm * K + k0 + kc * 8;
                    float4 a = *(const float4*)ap;
                    float4 b = *(const float4*)(ap + 4);
                    float af_[4] = {a.x, a.y, a.z, a.w}, bf_[4] = {b.x, b.y, b.z, b.w};
                    v = pack8(af_, bf_);
                }
                *(bf16x8*)((char*)Asm + row * 128 + 16 * (kc ^ (row & 7))) = v;
            }
        }
        __syncthreads();

        bf16x8 af[2][2], bfr[2][2];
#pragma unroll
        for (int i = 0; i < 2; ++i) {
#pragma unroll
            for (int kk = 0; kk < 2; ++kk) {
                int arow = wr * 32 + i * 16 + lr;
                af[i][kk]  = *(const bf16x8*)((char*)Asm + arow * 128 + 16 * ((kk * 4 + lg) ^ (arow & 7)));
                int brow = wc * 32 + i * 16 + lr;
                bfr[i][kk] = *(const bf16x8*)((char*)Bsm + brow * 128 + 16 * ((kk * 4 + lg) ^ (brow & 7)));
            }
        }
#pragma unroll
        for (int kk = 0; kk < 2; ++kk)
#pragma unroll
            for (int i = 0; i < 2; ++i)
#pragma unroll
                for (int j = 0; j < 2; ++j)
                    acc[i][j] = __builtin_amdgcn_mfma_f32_16x16x32_bf16(
                        af[i][kk], bfr[j][kk], acc[i][j], 0, 0, 0);
        __syncthreads();
    }

#pragma unroll
    for (int i = 0; i < 2; ++i) {
        int mbase = m0 + wr * 32 + i * 16 + lg * 4;
#pragma unroll
        for (int j = 0; j < 2; ++j) {
            int n = n0 + wc * 32 + j * 16 + lr;
            if (n >= Nreal) continue;
            float bn = bias[n];
#pragma unroll
            for (int r = 0; r < 4; ++r) {
                int m = mbase + r;
                if (m >= M) continue;
                float v = acc[i][j][r] + bn;
                if (RELU) v = fmaxf(v, 0.f);
                if (OUTBF16) ((unsigned short*)Cv)[(size_t)m * Nreal + n] = f2bf(v);
                else         ((float*)Cv)[(size_t)m * Nreal + n] = v;
            }
        }
    }
}

// =====================================================================
// LN over D=256: out = LN(a+b)*g + be; bf16 copy outh.
// =====================================================================
__global__ __launch_bounds__(256) void ln_kernel(
    const float* __restrict__ a, const float* __restrict__ b,
    const float* __restrict__ g, const float* __restrict__ be,
    float* __restrict__ out, unsigned short* __restrict__ outh)
{
    int row  = blockIdx.x * 4 + (threadIdx.x >> 6);
    int lane = threadIdx.x & 63;
    if (row >= MQ) return;

    const float4 va = *(const float4*)(a + (size_t)row * D + lane * 4);
    const float4 vb = *(const float4*)(b + (size_t)row * D + lane * 4);
    float x[4] = { va.x + vb.x, va.y + vb.y, va.z + vb.z, va.w + vb.w };

    float s = x[0] + x[1] + x[2] + x[3];
    float s2 = x[0]*x[0] + x[1]*x[1] + x[2]*x[2] + x[3]*x[3];
#pragma unroll
    for (int o = 32; o >= 1; o >>= 1) {
        s  += __shfl_xor(s,  o);
        s2 += __shfl_xor(s2, o);
    }
    float mean = s * (1.f / D);
    float var  = s2 * (1.f / D) - mean * mean;
    float rinv = rsqrtf(var + 1e-5f);

    float4 vg = *(const float4*)(g  + lane * 4);
    float4 vbe = *(const float4*)(be + lane * 4);
    float4 vo;
    vo.x = (x[0] - mean) * rinv * vg.x + vbe.x;
    vo.y = (x[1] - mean) * rinv * vg.y + vbe.y;
    vo.z = (x[2] - mean) * rinv * vg.z + vbe.z;
    vo.w = (x[3] - mean) * rinv * vg.w + vbe.w;
    *(float4*)(out + (size_t)row * D + lane * 4) = vo;

    ushort4 ho;
    ho.x = f2bf(vo.x); ho.y = f2bf(vo.y); ho.z = f2bf(vo.z); ho.w = f2bf(vo.w);
    *(ushort4*)(outh + (size_t)row * D + lane * 4) = ho;
}

// =====================================================================
// sample kernel with OPTIONAL inline bbox-refinement of the PREVIOUS layer.
// (r13-validated)
// =====================================================================
template<bool IREF>
__global__ __launch_bounds__(256) void sample_kernel(
    const unsigned short* __restrict__ value, const float* __restrict__ qoa,
    const float* __restrict__ ref_in,
    const unsigned short* __restrict__ t2,
    const float* __restrict__ Wb3, const float* __restrict__ bb3,
    float* __restrict__ ref_out,
    const float* __restrict__ svr,
    float* __restrict__ attn)
{
    __shared__ float refs[4];

    int nq = blockIdx.x;
    int h  = threadIdx.x >> 5;
    int dh = threadIdx.x & 31;
    int n  = nq / LQ;

    if (IREF) {
        if (threadIdx.x < 64) {
            int lane = threadIdx.x;
            float a0 = 0.f, a1 = 0.f, a2 = 0.f, a3 = 0.f;
            const unsigned short* tp = t2 + (size_t)nq * D;
#pragma unroll
            for (int kk = 0; kk < D / 64; ++kk) {
                int k = lane + kk * 64;
                float tv = bf2f(tp[k]);
                const float4 wrow = *(const float4*)(Wb3 + (size_t)k * 4);
                a0 = fmaf(tv, wrow.x, a0);
                a1 = fmaf(tv, wrow.y, a1);
                a2 = fmaf(tv, wrow.z, a2);
                a3 = fmaf(tv, wrow.w, a3);
            }
#pragma unroll
            for (int o = 32; o >= 1; o >>= 1) {
                a0 += __shfl_xor(a0, o);
                a1 += __shfl_xor(a1, o);
                a2 += __shfl_xor(a2, o);
                a3 += __shfl_xor(a3, o);
            }
            if (lane == 0) {
                float t3[4] = { a0 + bb3[0], a1 + bb3[1], a2 + bb3[2], a3 + bb3[3] };
#pragma unroll
                for (int c = 0; c < 4; ++c) {
                    float rp = ref_in[(size_t)nq * 4 + c];
                    float xc = fminf(fmaxf(rp, 0.f), 1.f);
                    float invsig = logf(fmaxf(xc, 1e-5f) / fmaxf(1.f - xc, 1e-5f));
                    float rv = 1.f / (1.f + expf(-(t3[c] + invsig)));
                    refs[c] = rv;
                    ref_out[(size_t)nq * 4 + c] = rv;
                }
            }
        }
        __syncthreads();
    }

    float vr0 = svr[n * 2 + 0], vr1 = svr[n * 2 + 1];
    float rr0, rr1, rr2, rr3;
    if (IREF) {
        rr0 = refs[0]; rr1 = refs[1]; rr2 = refs[2]; rr3 = refs[3];
    } else {
        rr0 = ref_in[nq * 4 + 0]; rr1 = ref_in[nq * 4 + 1];
        rr2 = ref_in[nq * 4 + 2]; rr3 = ref_in[nq * 4 + 3];
    }
    float r0 = rr0 * vr0;
    float r1 = rr1 * vr1;
    float r2 = rr2 * vr0;
    float r3 = rr3 * vr1;

    const float* qrow = qoa + (size_t)nq * 96;

    float lgt[4];
    float mx = -1e30f;
#pragma unroll
    for (int p = 0; p < 4; ++p) {
        lgt[p] = qrow[64 + h * 4 + p];
        mx = fmaxf(mx, lgt[p]);
    }
    float ssum = 0.f;
#pragma unroll
    for (int p = 0; p < 4; ++p) { lgt[p] = expf(lgt[p] - mx); ssum += lgt[p]; }
    float sinv = 1.f / ssum;

    const unsigned short* vbase = value + (size_t)n * LEN * D + h * DH + dh;
    float acc = 0.f;

#pragma unroll
    for (int p = 0; p < NPTS; ++p) {
        float ox = qrow[h * 8 + p * 2 + 0];
        float oy = qrow[h * 8 + p * 2 + 1];
        float lx = r0 + ox * (1.f / NPTS) * r2 * 0.5f;
        float ly = r1 + oy * (1.f / NPTS) * r3 * 0.5f;
        float w  = lgt[p] * sinv;

        float x = lx * W_ - 0.5f;
        float y = ly * H_ - 0.5f;
        x = fminf(fmaxf(x, -1e4f), 1e4f);
        y = fminf(fmaxf(y, -1e4f), 1e4f);
        float x0f = floorf(x), y0f = floorf(y);
        float wx = x - x0f, wy = y - y0f;
        int x0 = (int)x0f, y0 = (int)y0f;

        float v00 = 0.f, v10 = 0.f, v01 = 0.f, v11 = 0.f;
        bool xin0 = (x0 >= 0 && x0 < W_);
        bool xin1 = (x0 + 1 >= 0 && x0 + 1 < W_);
        bool yin0 = (y0 >= 0 && y0 < H_);
        bool yin1 = (y0 + 1 >= 0 && y0 + 1 < H_);
        if (xin0 && yin0) v00 = bf2f(vbase[(size_t)(y0 * W_ + x0) * D]);
        if (xin1 && yin0) v10 = bf2f(vbase[(size_t)(y0 * W_ + x0 + 1) * D]);
        if (xin0 && yin1) v01 = bf2f(vbase[(size_t)((y0 + 1) * W_ + x0) * D]);
        if (xin1 && yin1) v11 = bf2f(vbase[(size_t)((y0 + 1) * W_ + x0 + 1) * D]);

        float bil = v00 * (1.f - wx) * (1.f - wy)
                  + v10 * wx * (1.f - wy)
                  + v01 * (1.f - wx) * wy
                  + v11 * wx * wy;
        acc += w * bil;
    }
    attn[(size_t)nq * D + h * DH + dh] = acc;
}

// =====================================================================
// bbox final (LAST layer only)
// =====================================================================
__global__ __launch_bounds__(256) void bbox_kernel(
    const unsigned short* __restrict__ t2, const float* __restrict__ Wb3,
    const float* __restrict__ bb3, const float* __restrict__ ref_prev,
    float* __restrict__ ref_out)
{
    int row  = blockIdx.x * 4 + (threadIdx.x >> 6);
    int lane = threadIdx.x & 63;
    if (row >= MQ) return;

    float acc0 = 0.f, acc1 = 0.f, acc2 = 0.f, acc3 = 0.f;
    const unsigned short* tp = t2 + (size_t)row * D;
#pragma unroll
    for (int kk = 0; kk < D / 64; ++kk) {
        int k = lane + kk * 64;
        float tv = bf2f(tp[k]);
        const float4 wrow = *(const float4*)(Wb3 + (size_t)k * 4);
        acc0 = fmaf(tv, wrow.x, acc0);
        acc1 = fmaf(tv, wrow.y, acc1);
        acc2 = fmaf(tv, wrow.z, acc2);
        acc3 = fmaf(tv, wrow.w, acc3);
    }
#pragma unroll
    for (int o = 32; o >= 1; o >>= 1) {
        acc0 += __shfl_xor(acc0, o);
        acc1 += __shfl_xor(acc1, o);
        acc2 += __shfl_xor(acc2, o);
        acc3 += __shfl_xor(acc3, o);
    }
    if (lane == 0) {
        float t3[4] = { acc0 + bb3[0], acc1 + bb3[1], acc2 + bb3[2], acc3 + bb3[3] };
#pragma unroll
        for (int c = 0; c < 4; ++c) {
            float rp = ref_prev[(size_t)row * 4 + c];
            float xc = fminf(fmaxf(rp, 0.f), 1.f);
            float invsig = logf(fmaxf(xc, 1e-5f) / fmaxf(1.f - xc, 1e-5f));
            float sarg = t3[c] + invsig;
            ref_out[(size_t)row * 4 + c] = 1.f / (1.f + expf(-sarg));
        }
    }
}

// =====================================================================
// launcher
// =====================================================================
extern "C" void kernel_launch(void* const* d_in, const int* in_sizes, int n_in,
                              void* d_out, int out_size, void* d_ws, size_t ws_size,
                              hipStream_t stream)
{
    const float* tgt    = (const float*)d_in[0];
    const float* refpts = (const float*)d_in[1];
    const float* src    = (const float*)d_in[2];
    const float* svr    = (const float*)d_in[3];
    const float* qpos   = (const float*)d_in[4];
    const float* Wo     = (const float*)d_in[5];
    const float* bo     = (const float*)d_in[6];
    const float* Wa     = (const float*)d_in[7];
    const float* ba     = (const float*)d_in[8];
    const float* Wv     = (const float*)d_in[9];
    const float* bv     = (const float*)d_in[10];
    const float* Wout   = (const float*)d_in[11];
    const float* bout   = (const float*)d_in[12];
    const float* g1     = (const float*)d_in[13];
    const float* b1     = (const float*)d_in[14];
    const float* Wfc    = (const float*)d_in[15];
    const float* bfc    = (const float*)d_in[16];
    const float* Wproj  = (const float*)d_in[17];
    const float* bproj  = (const float*)d_in[18];
    const float* g2     = (const float*)d_in[19];
    const float* b2     = (const float*)d_in[20];
    const float* Wb1    = (const float*)d_in[21];
    const float* bb1    = (const float*)d_in[22];
    const float* Wb2    = (const float*)d_in[23];
    const float* bb2    = (const float*)d_in[24];
    const float* Wb3    = (const float*)d_in[25];
    const float* bb3    = (const float*)d_in[26];
    const unsigned char* mask = (const unsigned char*)d_in[29];

    float* outp  = (float*)d_out;
    float* inter     = outp;                             // (6, N, LQ, D)
    float* inter_ref = outp + (size_t)NLAYERS * MQ * D;  // (6, N, LQ, 4)

    // workspace carve-up
    char* wsb = (char*)d_ws;
    unsigned short* value    = (unsigned short*)wsb;  wsb += (size_t)MV * D * 2;  // 32 MiB
    unsigned short* src_bf16 = (unsigned short*)wsb;  wsb += (size_t)MV * D * 2;  // 32 MiB
    unsigned short* WvT      = (unsigned short*)wsb;  wsb += (size_t)NLAYERS * D * D * 2;
    unsigned short* WoaT     = (unsigned short*)wsb;  wsb += (size_t)NLAYERS * 128 * D * 2;
    unsigned short* WoutT    = (unsigned short*)wsb;  wsb += (size_t)NLAYERS * D * D * 2;
    unsigned short* WfcT     = (unsigned short*)wsb;  wsb += (size_t)NLAYERS * DFF * D * 2;
    unsigned short* WprojT   = (unsigned short*)wsb;  wsb += (size_t)NLAYERS * D * DFF * 2;
    unsigned short* Wb1T     = (unsigned short*)wsb;  wsb += (size_t)NLAYERS * D * D * 2;
    unsigned short* Wb2T     = (unsigned short*)wsb;  wsb += (size_t)NLAYERS * D * D * 2;
    unsigned short* hmlp     = (unsigned short*)wsb;  wsb += (size_t)MQ * DFF * 2;
    unsigned short* t1b      = (unsigned short*)wsb;  wsb += (size_t)MQ * D * 2;
    unsigned short* t2b      = (unsigned short*)wsb;  wsb += (size_t)MQ * D * 2;
    unsigned short* x1h      = (unsigned short*)wsb;  wsb += (size_t)MQ * D * 2;
    unsigned short* x2h      = (unsigned short*)wsb;  wsb += (size_t)MQ * D * 2;
    float* boa   = (float*)wsb;        wsb += (size_t)NLAYERS * 128 * 4;
    float* ws    = (float*)wsb;
    float* qoab  = ws;                 size_t o = (size_t)MQ * 96;
    float* attnb = ws + o;             o += (size_t)MQ * D;
    float* tmpb  = ws + o;             o += (size_t)MQ * D;
    float* x1b   = ws + o;             o += (size_t)MQ * D;

    // ---- one-time conversions (6 dispatches) ----
    cvt_bf16_kernel<<<(MV * D / 8 + 255) / 256, 256, 0, stream>>>(src, src_bf16, MV * D / 8);
    {
        int t = NLAYERS * D * D;
        wt_cvt4_kernel<<<(t + 255) / 256, 256, 0, stream>>>(
            Wv, Wout, Wb1, Wb2, WvT, WoutT, Wb1T, Wb2T);
        t = NLAYERS * DFF * D;
        wt_cvt_kernel<<<(t + 255) / 256, 256, 0, stream>>>(Wfc,   WfcT,   D,   DFF, DFF, t);
        wt_cvt_kernel<<<(t + 255) / 256, 256, 0, stream>>>(Wproj, WprojT, DFF, D,   D,   t);
        t = NLAYERS * 128 * D;
        woat_kernel<<<(t + 255) / 256, 256, 0, stream>>>(Wo, Wa, WoaT);
        bias_concat_kernel<<<(NLAYERS * 128 + 255) / 256, 256, 0, stream>>>(bo, ba, boa);
    }

    // ---- layer-0 prologue: value(0) + qoa(0) ----
    fused_vq_kernel<false><<<VBLK + QBLK, 256, 0, stream>>>(
        src_bf16, WvT, bv, mask, value,
        tgt, qpos, WoaT, boa, qoab,
        nullptr, nullptr, nullptr, nullptr);

    for (int l = 0; l < NLAYERS; ++l) {
        const float* out_prev = (l == 0) ? tgt : inter + (size_t)(l - 1) * MQ * D;
        float* inter_l = inter + (size_t)l * MQ * D;

        // 1) sample (+ inline ref(l-1) refinement for l>=1)
        if (l == 0) {
            sample_kernel<false><<<MQ, 256, 0, stream>>>(
                value, qoab, refpts, nullptr, nullptr, nullptr, nullptr, svr, attnb);
        } else {
            const float* ref_pp = (l == 1) ? refpts : inter_ref + (size_t)(l - 2) * MQ * 4;
            sample_kernel<true><<<MQ, 256, 0, stream>>>(
                value, qoab, ref_pp, t2b,
                Wb3 + (size_t)(l - 1) * D * 4, bb3 + (size_t)(l - 1) * 4,
                inter_ref + (size_t)(l - 1) * MQ * 4, svr, attnb);
        }

        // 2) attn @ Wout + bout  (228 blocks)
        gemm_q_mfma<false,false,false><<<dim3(4, MB), 256, 0, stream>>>(
            attnb, WoutT + (size_t)l * D * D, bout + (size_t)l * D, tmpb, MQ, D, D);

        // 3) x1 = LN(out_prev + tmp) -> fp32 + bf16
        ln_kernel<<<MQ / 4, 256, 0, stream>>>(
            out_prev, tmpb, g1 + (size_t)l * D, b1 + (size_t)l * D, x1b, x1h);

        // 4) h = relu(x1h @ Wfc + bfc) -> bf16  (128x128 tile, 232 blocks)
        gemm_fc_mfma<<<dim3(DFF / 128, MB128), 256, 0, stream>>>(
            x1h, WfcT + (size_t)l * DFF * D, bfc + (size_t)l * DFF, hmlp);

        // 5) proj: h @ Wproj + bproj  (228 blocks)
        gemm_q_mfma<true,false,false><<<dim3(4, MB), 256, 0, stream>>>(
            hmlp, WprojT + (size_t)l * D * DFF, bproj + (size_t)l * D, tmpb, MQ, D, DFF);

        // 6) x2 = LN(x1 + tmp) -> inter[l] fp32 + bf16
        ln_kernel<<<MQ / 4, 256, 0, stream>>>(
            x1b, tmpb, g2 + (size_t)l * D, b2 + (size_t)l * D, inter_l, x2h);

        // 7) b1(l) overlapped with value(l+1)+qoa(l+1)  [l<5]; plain b1 on last layer
        if (l < NLAYERS - 1) {
            fused_vq_kernel<true><<<VBLK + QBLK + BBLK, 256, 0, stream>>>(
                src_bf16, WvT + (size_t)(l + 1) * D * D, bv + (size_t)(l + 1) * D, mask, value,
                inter_l, qpos, WoaT + (size_t)(l + 1) * 128 * D, boa + (size_t)(l + 1) * 128, qoab,
                x2h, Wb1T + (size_t)l * D * D, bb1 + (size_t)l * D, t1b);
        } else {
            gemm_q_mfma<true,true,true><<<dim3(4, MB), 256, 0, stream>>>(
                x2h, Wb1T + (size_t)l * D * D, bb1 + (size_t)l * D, t1b, MQ, D, D);
        }

        // 8) t2 = relu(t1 @ Wb2 + bb2) -> bf16
        gemm_q_mfma<true,true,true><<<dim3(4, MB), 256, 0, stream>>>(
            t1b, Wb2T + (size_t)l * D * D, bb2 + (size_t)l * D, t2b, MQ, D, D);

        // 9) bbox only for the LAST layer
        if (l == NLAYERS - 1) {
            bbox_kernel<<<MQ / 4, 256, 0, stream>>>(
                t2b, Wb3 + (size_t)l * D * 4, bb3 + (size_t)l * 4,
                inter_ref + (size_t)(l - 1) * MQ * 4, inter_ref + (size_t)l * MQ * 4);
        }
    }
}

// Round 15
// 576.468 us; speedup vs baseline: 1.0554x; 1.0554x over previous
//
#include <hip/hip_runtime.h>
#include <hip/hip_bf16.h>
#include <math.h>

// ---- problem constants ----
constexpr int N_    = 4;
constexpr int LQ    = 900;
constexpr int D     = 256;
constexpr int HEADS = 8;
constexpr int DH    = 32;
constexpr int NPTS  = 4;
constexpr int LEN   = 16384;   // 128*128
constexpr int H_    = 128;
constexpr int W_    = 128;
constexpr int DFF   = 1024;
constexpr int NLAYERS = 6;
constexpr int MQ    = N_ * LQ;   // 3600
constexpr int MV    = N_ * LEN;  // 65536
constexpr int MB    = (MQ + 63) / 64;   // 57
constexpr int VBLK  = (D / 128) * (MV / 128);  // 1024 value blocks
constexpr int QBLK  = 2 * MB;                  // 114 qoa blocks
constexpr int BBLK  = 4 * MB;                  // 228 b1 blocks

typedef __attribute__((ext_vector_type(8))) short bf16x8;
typedef __attribute__((ext_vector_type(4))) float f32x4;

static __device__ __forceinline__ unsigned short f2bf(float v) {
    __hip_bfloat16 h = __float2bfloat16(v);
    return *(unsigned short*)&h;
}
static __device__ __forceinline__ float bf2f(unsigned short u) {
    __hip_bfloat16 h = *(__hip_bfloat16*)&u;
    return __bfloat162float(h);
}
static __device__ __forceinline__ bf16x8 pack8(const float* a, const float* b4) {
    union { bf16x8 v; unsigned short u[8]; } o;
    o.u[0] = f2bf(a[0]); o.u[1] = f2bf(a[1]); o.u[2] = f2bf(a[2]); o.u[3] = f2bf(a[3]);
    o.u[4] = f2bf(b4[0]); o.u[5] = f2bf(b4[1]); o.u[6] = f2bf(b4[2]); o.u[7] = f2bf(b4[3]);
    return o.v;
}

// async global->LDS, 16 B per lane (LDS dest wave-uniform base + lane*16)
static __device__ __forceinline__ void gload_lds16(const void* gaddr, void* laddr) {
    __builtin_amdgcn_global_load_lds(
        (const __attribute__((address_space(1))) unsigned int*)gaddr,
        (__attribute__((address_space(3))) unsigned int*)laddr,
        16, 0, 0);
}

// =====================================================================
// fp32 -> bf16 conversion (contiguous), n8 = count/8
// =====================================================================
__global__ __launch_bounds__(256) void cvt_bf16_kernel(
    const float* __restrict__ in, unsigned short* __restrict__ out, int n8)
{
    int i = blockIdx.x * 256 + threadIdx.x;
    if (i >= n8) return;
    float4 a = ((const float4*)in)[i * 2];
    float4 b = ((const float4*)in)[i * 2 + 1];
    float af[4] = {a.x, a.y, a.z, a.w}, bff[4] = {b.x, b.y, b.z, b.w};
    *(bf16x8*)(out + (size_t)i * 8) = pack8(af, bff);
}

// =====================================================================
// 4x D x D weight transpose+cvt in one dispatch (Wv, Wout, Wb1, Wb2)
// =====================================================================
__global__ __launch_bounds__(256) void wt_cvt4_kernel(
    const float* __restrict__ W0, const float* __restrict__ W1,
    const float* __restrict__ W2, const float* __restrict__ W3,
    unsigned short* __restrict__ T0, unsigned short* __restrict__ T1,
    unsigned short* __restrict__ T2, unsigned short* __restrict__ T3)
{
    int i = blockIdx.x * 256 + threadIdx.x;
    if (i >= NLAYERS * D * D) return;
    int k = i & (D - 1);
    int n = (i >> 8) & (D - 1);
    int l = i >> 16;
    size_t si = (size_t)l * D * D + (size_t)k * D + n;
    T0[i] = f2bf(W0[si]);
    T1[i] = f2bf(W1[si]);
    T2[i] = f2bf(W2[si]);
    T3[i] = f2bf(W3[si]);
}

// =====================================================================
// generic weight transpose+cvt: W (L,K,N) fp32 -> WT (L,Npad,K) bf16
// =====================================================================
__global__ __launch_bounds__(256) void wt_cvt_kernel(
    const float* __restrict__ W, unsigned short* __restrict__ WT,
    int K, int Nr, int Npad, int total)
{
    int i = blockIdx.x * 256 + threadIdx.x;
    if (i >= total) return;
    int k = i % K;
    int n = (i / K) % Npad;
    int l = i / (K * Npad);
    WT[i] = (n < Nr) ? f2bf(W[((size_t)l * K + k) * Nr + n]) : (unsigned short)0;
}

// =====================================================================
// WoaT: rows 0..63 = Wo^T (N=64), rows 64..95 = Wa^T (N=32), 96..127 = 0
// =====================================================================
__global__ __launch_bounds__(256) void woat_kernel(
    const float* __restrict__ Wo, const float* __restrict__ Wa,
    unsigned short* __restrict__ WoaT)
{
    int i = blockIdx.x * 256 + threadIdx.x;
    if (i >= NLAYERS * 128 * D) return;
    int k = i % D;
    int n = (i / D) & 127;
    int l = i / (D * 128);
    float v = 0.f;
    if (n < 64)      v = Wo[((size_t)l * D + k) * 64 + n];
    else if (n < 96) v = Wa[((size_t)l * D + k) * 32 + (n - 64)];
    WoaT[i] = f2bf(v);
}

__global__ __launch_bounds__(256) void bias_concat_kernel(
    const float* __restrict__ bo, const float* __restrict__ ba, float* __restrict__ boa)
{
    int i = blockIdx.x * 256 + threadIdx.x;
    if (i >= NLAYERS * 128) return;
    int n = i & 127;
    int l = i >> 7;
    float v = 0.f;
    if (n < 64)      v = bo[l * 64 + n];
    else if (n < 96) v = ba[l * 32 + (n - 64)];
    boa[i] = v;
}

// =====================================================================
// 3-way fused dispatch (r12-validated):
//   [0, VBLK):           value GEMM layer l+1 (128x128, XCD pairing)
//   [VBLK, VBLK+QBLK):   qoa GEMM layer l+1 (64x64, fused add)
//   [VBLK+QBLK, +BBLK):  b1 GEMM layer l (64x64, bf16 A, relu, bf16 out)
// =====================================================================
template<bool HAS_B1>
__global__ __launch_bounds__(256) void fused_vq_kernel(
    const unsigned short* __restrict__ A, const unsigned short* __restrict__ Bt,
    const float* __restrict__ bias, const unsigned char* __restrict__ mask,
    unsigned short* __restrict__ C,
    const float* __restrict__ Aq, const float* __restrict__ A2q,
    const unsigned short* __restrict__ Btq, const float* __restrict__ biasq,
    float* __restrict__ Cq,
    const unsigned short* __restrict__ Ab1, const unsigned short* __restrict__ Btb1,
    const float* __restrict__ biasb1, unsigned short* __restrict__ Cb1)
{
    __shared__ unsigned short Asm[128 * 64];
    __shared__ unsigned short Bsm[128 * 64];

    const int bid  = blockIdx.x;
    const int tid  = threadIdx.x;
    const int wave = tid >> 6;
    const int lane = tid & 63;
    const int lg   = lane >> 4;
    const int lr   = lane & 15;

    if (bid < VBLK) {
        const int y  = (bid >> 4) * 8 + (bid & 7);
        const int x  = (bid >> 3) & 1;
        const int m0 = y * 128;
        const int n0 = x * 128;
        const int wr = wave >> 1;
        const int wc = wave & 1;

        f32x4 acc[4][4];
#pragma unroll
        for (int i = 0; i < 4; ++i)
#pragma unroll
            for (int j = 0; j < 4; ++j) acc[i][j] = (f32x4){0.f, 0.f, 0.f, 0.f};

        for (int k0 = 0; k0 < D; k0 += 64) {
#pragma unroll
            for (int it = 0; it < 4; ++it) {
                int c   = tid + it * 256;
                int row = c >> 3;
                int kch = (c & 7) ^ (row & 7);
                unsigned ldsoff = (unsigned)(it * 256 + wave * 64) * 16;
                gload_lds16(A  + (size_t)(m0 + row) * D + k0 + kch * 8, (char*)Asm + ldsoff);
                gload_lds16(Bt + (size_t)(n0 + row) * D + k0 + kch * 8, (char*)Bsm + ldsoff);
            }
            __syncthreads();

            bf16x8 af[4][2], bfr[4][2];
#pragma unroll
            for (int i = 0; i < 4; ++i) {
#pragma unroll
                for (int kk = 0; kk < 2; ++kk) {
                    int arow = wr * 64 + i * 16 + lr;
                    af[i][kk]  = *(const bf16x8*)((char*)Asm + arow * 128 + 16 * ((kk * 4 + lg) ^ (arow & 7)));
                    int brow = wc * 64 + i * 16 + lr;
                    bfr[i][kk] = *(const bf16x8*)((char*)Bsm + brow * 128 + 16 * ((kk * 4 + lg) ^ (brow & 7)));
                }
            }
#pragma unroll
            for (int kk = 0; kk < 2; ++kk)
#pragma unroll
                for (int i = 0; i < 4; ++i)
#pragma unroll
                    for (int j = 0; j < 4; ++j)
                        acc[i][j] = __builtin_amdgcn_mfma_f32_16x16x32_bf16(
                            af[i][kk], bfr[j][kk], acc[i][j], 0, 0, 0);
            __syncthreads();
        }

#pragma unroll
        for (int i = 0; i < 4; ++i) {
            int mbase = m0 + wr * 64 + i * 16 + lg * 4;
#pragma unroll
            for (int j = 0; j < 4; ++j) {
                int n = n0 + wc * 64 + j * 16 + lr;
                float bn = bias[n];
#pragma unroll
                for (int r = 0; r < 4; ++r) {
                    int m = mbase + r;
                    float v = acc[i][j][r] + bn;
                    if (mask[m]) v = 0.f;
                    C[(size_t)m * D + n] = f2bf(v);
                }
            }
        }
    } else if (bid < VBLK + QBLK) {
        const int qb = bid - VBLK;
        const int n0 = (qb & 1) * 64;
        const int m0 = (qb >> 1) * 64;
        const int wr = wave >> 1;
        const int wc = wave & 1;

        f32x4 acc[2][2];
#pragma unroll
        for (int i = 0; i < 2; ++i)
#pragma unroll
            for (int j = 0; j < 2; ++j) acc[i][j] = (f32x4){0.f, 0.f, 0.f, 0.f};

        for (int k0 = 0; k0 < D; k0 += 64) {
#pragma unroll
            for (int it = 0; it < 2; ++it) {
                int c   = tid + it * 256;
                int row = c >> 3;
                int kc  = c & 7;
                int kch = kc ^ (row & 7);
                unsigned ldsoff = (unsigned)(it * 256 + wave * 64) * 16;
                gload_lds16(Btq + (size_t)(n0 + row) * D + k0 + kch * 8, (char*)Bsm + ldsoff);
                int gm = m0 + row;
                bf16x8 v = (bf16x8){0,0,0,0,0,0,0,0};
                if (gm < MQ) {
                    const float* ap = Aq  + (size_t)gm * D + k0 + kc * 8;
                    const float* qp = A2q + (size_t)gm * D + k0 + kc * 8;
                    float4 a = *(const float4*)ap;
                    float4 b = *(const float4*)(ap + 4);
                    float4 qa = *(const float4*)qp;
                    float4 qb4 = *(const float4*)(qp + 4);
                    a.x += qa.x; a.y += qa.y; a.z += qa.z; a.w += qa.w;
                    b.x += qb4.x; b.y += qb4.y; b.z += qb4.z; b.w += qb4.w;
                    float af_[4] = {a.x, a.y, a.z, a.w}, bf_[4] = {b.x, b.y, b.z, b.w};
                    v = pack8(af_, bf_);
                }
                *(bf16x8*)((char*)Asm + row * 128 + 16 * (kc ^ (row & 7))) = v;
            }
            __syncthreads();

            bf16x8 af[2][2], bfr[2][2];
#pragma unroll
            for (int i = 0; i < 2; ++i) {
#pragma unroll
                for (int kk = 0; kk < 2; ++kk) {
                    int arow = wr * 32 + i * 16 + lr;
                    af[i][kk]  = *(const bf16x8*)((char*)Asm + arow * 128 + 16 * ((kk * 4 + lg) ^ (arow & 7)));
                    int brow = wc * 32 + i * 16 + lr;
                    bfr[i][kk] = *(const bf16x8*)((char*)Bsm + brow * 128 + 16 * ((kk * 4 + lg) ^ (brow & 7)));
                }
            }
#pragma unroll
            for (int kk = 0; kk < 2; ++kk)
#pragma unroll
                for (int i = 0; i < 2; ++i)
#pragma unroll
                    for (int j = 0; j < 2; ++j)
                        acc[i][j] = __builtin_amdgcn_mfma_f32_16x16x32_bf16(
                            af[i][kk], bfr[j][kk], acc[i][j], 0, 0, 0);
            __syncthreads();
        }

#pragma unroll
        for (int i = 0; i < 2; ++i) {
            int mbase = m0 + wr * 32 + i * 16 + lg * 4;
#pragma unroll
            for (int j = 0; j < 2; ++j) {
                int n = n0 + wc * 32 + j * 16 + lr;
                if (n >= 96) continue;
                float bn = biasq[n];
#pragma unroll
                for (int r = 0; r < 4; ++r) {
                    int m = mbase + r;
                    if (m >= MQ) continue;
                    Cq[(size_t)m * 96 + n] = acc[i][j][r] + bn;
                }
            }
        }
    } else if (HAS_B1) {
        const int bb = bid - VBLK - QBLK;
        const int n0 = (bb & 3) * 64;
        const int m0 = (bb >> 2) * 64;
        const int wr = wave >> 1;
        const int wc = wave & 1;

        f32x4 acc[2][2];
#pragma unroll
        for (int i = 0; i < 2; ++i)
#pragma unroll
            for (int j = 0; j < 2; ++j) acc[i][j] = (f32x4){0.f, 0.f, 0.f, 0.f};

        for (int k0 = 0; k0 < D; k0 += 64) {
#pragma unroll
            for (int it = 0; it < 2; ++it) {
                int c   = tid + it * 256;
                int row = c >> 3;
                int kch = (c & 7) ^ (row & 7);
                unsigned ldsoff = (unsigned)(it * 256 + wave * 64) * 16;
                gload_lds16(Btb1 + (size_t)(n0 + row) * D + k0 + kch * 8, (char*)Bsm + ldsoff);
                gload_lds16(Ab1  + (size_t)(m0 + row) * D + k0 + kch * 8, (char*)Asm + ldsoff);
            }
            __syncthreads();

            bf16x8 af[2][2], bfr[2][2];
#pragma unroll
            for (int i = 0; i < 2; ++i) {
#pragma unroll
                for (int kk = 0; kk < 2; ++kk) {
                    int arow = wr * 32 + i * 16 + lr;
                    af[i][kk]  = *(const bf16x8*)((char*)Asm + arow * 128 + 16 * ((kk * 4 + lg) ^ (arow & 7)));
                    int brow = wc * 32 + i * 16 + lr;
                    bfr[i][kk] = *(const bf16x8*)((char*)Bsm + brow * 128 + 16 * ((kk * 4 + lg) ^ (brow & 7)));
                }
            }
#pragma unroll
            for (int kk = 0; kk < 2; ++kk)
#pragma unroll
                for (int i = 0; i < 2; ++i)
#pragma unroll
                    for (int j = 0; j < 2; ++j)
                        acc[i][j] = __builtin_amdgcn_mfma_f32_16x16x32_bf16(
                            af[i][kk], bfr[j][kk], acc[i][j], 0, 0, 0);
            __syncthreads();
        }

#pragma unroll
        for (int i = 0; i < 2; ++i) {
            int mbase = m0 + wr * 32 + i * 16 + lg * 4;
#pragma unroll
            for (int j = 0; j < 2; ++j) {
                int n = n0 + wc * 32 + j * 16 + lr;
#pragma unroll
                for (int r = 0; r < 4; ++r) {
                    int m = mbase + r;
                    if (m >= MQ) continue;
                    float v = fmaxf(acc[i][j][r] + biasb1[n], 0.f);
                    Cb1[(size_t)m * D + n] = f2bf(v);
                }
            }
        }
    }
}

// =====================================================================
// MFMA query GEMM: C[M,Nreal] = A[M,K] @ Bt^T + bias (+relu). (r10-validated)
// =====================================================================
template<bool ABF16, bool RELU, bool OUTBF16>
__global__ __launch_bounds__(256) void gemm_q_mfma(
    const void* __restrict__ Av,
    const unsigned short* __restrict__ Bt, const float* __restrict__ bias,
    void* __restrict__ Cv, int M, int Nreal, int K)
{
    __shared__ unsigned short Asm[64 * 64];
    __shared__ unsigned short Bsm[64 * 64];

    const int tid  = threadIdx.x;
    const int m0   = blockIdx.y * 64;
    const int n0   = blockIdx.x * 64;
    const int wave = tid >> 6;
    const int lane = tid & 63;
    const int wr   = wave >> 1;
    const int wc   = wave & 1;
    const int lg   = lane >> 4;
    const int lr   = lane & 15;

    f32x4 acc[2][2];
#pragma unroll
    for (int i = 0; i < 2; ++i)
#pragma unroll
        for (int j = 0; j < 2; ++j) acc[i][j] = (f32x4){0.f, 0.f, 0.f, 0.f};

    for (int k0 = 0; k0 < K; k0 += 64) {
#pragma unroll
        for (int it = 0; it < 2; ++it) {
            int c   = tid + it * 256;
            int row = c >> 3;
            int kch = (c & 7) ^ (row & 7);
            unsigned ldsoff = (unsigned)(it * 256 + wave * 64) * 16;
            gload_lds16(Bt + (size_t)(n0 + row) * K + k0 + kch * 8, (char*)Bsm + ldsoff);
            if (ABF16) {
                gload_lds16((const unsigned short*)Av + (size_t)(m0 + row) * K + k0 + kch * 8,
                            (char*)Asm + ldsoff);
            } else {
                int kc = c & 7;
                int gm = m0 + row;
                bf16x8 v = (bf16x8){0,0,0,0,0,0,0,0};
                if (gm < M) {
                    const float* ap = (const float*)Av + (size_t)gm * K + k0 + kc * 8;
                    float4 a = *(const float4*)ap;
                    float4 b = *(const float4*)(ap + 4);
                    float af_[4] = {a.x, a.y, a.z, a.w}, bf_[4] = {b.x, b.y, b.z, b.w};
                    v = pack8(af_, bf_);
                }
                *(bf16x8*)((char*)Asm + row * 128 + 16 * (kc ^ (row & 7))) = v;
            }
        }
        __syncthreads();

        bf16x8 af[2][2], bfr[2][2];
#pragma unroll
        for (int i = 0; i < 2; ++i) {
#pragma unroll
            for (int kk = 0; kk < 2; ++kk) {
                int arow = wr * 32 + i * 16 + lr;
                af[i][kk]  = *(const bf16x8*)((char*)Asm + arow * 128 + 16 * ((kk * 4 + lg) ^ (arow & 7)));
                int brow = wc * 32 + i * 16 + lr;
                bfr[i][kk] = *(const bf16x8*)((char*)Bsm + brow * 128 + 16 * ((kk * 4 + lg) ^ (brow & 7)));
            }
        }
#pragma unroll
        for (int kk = 0; kk < 2; ++kk)
#pragma unroll
            for (int i = 0; i < 2; ++i)
#pragma unroll
                for (int j = 0; j < 2; ++j)
                    acc[i][j] = __builtin_amdgcn_mfma_f32_16x16x32_bf16(
                        af[i][kk], bfr[j][kk], acc[i][j], 0, 0, 0);
        __syncthreads();
    }

#pragma unroll
    for (int i = 0; i < 2; ++i) {
        int mbase = m0 + wr * 32 + i * 16 + lg * 4;
#pragma unroll
        for (int j = 0; j < 2; ++j) {
            int n = n0 + wc * 32 + j * 16 + lr;
            if (n >= Nreal) continue;
            float bn = bias[n];
#pragma unroll
            for (int r = 0; r < 4; ++r) {
                int m = mbase + r;
                if (m >= M) continue;
                float v = acc[i][j][r] + bn;
                if (RELU) v = fmaxf(v, 0.f);
                if (OUTBF16) ((unsigned short*)Cv)[(size_t)m * Nreal + n] = f2bf(v);
                else         ((float*)Cv)[(size_t)m * Nreal + n] = v;
            }
        }
    }
}

// =====================================================================
// LN over D=256: out = LN(a+b)*g + be; bf16 copy outh.
// =====================================================================
__global__ __launch_bounds__(256) void ln_kernel(
    const float* __restrict__ a, const float* __restrict__ b,
    const float* __restrict__ g, const float* __restrict__ be,
    float* __restrict__ out, unsigned short* __restrict__ outh)
{
    int row  = blockIdx.x * 4 + (threadIdx.x >> 6);
    int lane = threadIdx.x & 63;
    if (row >= MQ) return;

    const float4 va = *(const float4*)(a + (size_t)row * D + lane * 4);
    const float4 vb = *(const float4*)(b + (size_t)row * D + lane * 4);
    float x[4] = { va.x + vb.x, va.y + vb.y, va.z + vb.z, va.w + vb.w };

    float s = x[0] + x[1] + x[2] + x[3];
    float s2 = x[0]*x[0] + x[1]*x[1] + x[2]*x[2] + x[3]*x[3];
#pragma unroll
    for (int o = 32; o >= 1; o >>= 1) {
        s  += __shfl_xor(s,  o);
        s2 += __shfl_xor(s2, o);
    }
    float mean = s * (1.f / D);
    float var  = s2 * (1.f / D) - mean * mean;
    float rinv = rsqrtf(var + 1e-5f);

    float4 vg = *(const float4*)(g  + lane * 4);
    float4 vbe = *(const float4*)(be + lane * 4);
    float4 vo;
    vo.x = (x[0] - mean) * rinv * vg.x + vbe.x;
    vo.y = (x[1] - mean) * rinv * vg.y + vbe.y;
    vo.z = (x[2] - mean) * rinv * vg.z + vbe.z;
    vo.w = (x[3] - mean) * rinv * vg.w + vbe.w;
    *(float4*)(out + (size_t)row * D + lane * 4) = vo;

    ushort4 ho;
    ho.x = f2bf(vo.x); ho.y = f2bf(vo.y); ho.z = f2bf(vo.z); ho.w = f2bf(vo.w);
    *(ushort4*)(outh + (size_t)row * D + lane * 4) = ho;
}

// =====================================================================
// sample kernel with OPTIONAL inline bbox-refinement of the PREVIOUS layer.
// Writes attn as bf16 (same rounding as downstream staging did).
// =====================================================================
template<bool IREF>
__global__ __launch_bounds__(256) void sample_kernel(
    const unsigned short* __restrict__ value, const float* __restrict__ qoa,
    const float* __restrict__ ref_in,
    const unsigned short* __restrict__ t2,
    const float* __restrict__ Wb3, const float* __restrict__ bb3,
    float* __restrict__ ref_out,
    const float* __restrict__ svr,
    unsigned short* __restrict__ attn)
{
    __shared__ float refs[4];

    int nq = blockIdx.x;
    int h  = threadIdx.x >> 5;
    int dh = threadIdx.x & 31;
    int n  = nq / LQ;

    if (IREF) {
        if (threadIdx.x < 64) {
            int lane = threadIdx.x;
            float a0 = 0.f, a1 = 0.f, a2 = 0.f, a3 = 0.f;
            const unsigned short* tp = t2 + (size_t)nq * D;
#pragma unroll
            for (int kk = 0; kk < D / 64; ++kk) {
                int k = lane + kk * 64;
                float tv = bf2f(tp[k]);
                const float4 wrow = *(const float4*)(Wb3 + (size_t)k * 4);
                a0 = fmaf(tv, wrow.x, a0);
                a1 = fmaf(tv, wrow.y, a1);
                a2 = fmaf(tv, wrow.z, a2);
                a3 = fmaf(tv, wrow.w, a3);
            }
#pragma unroll
            for (int o = 32; o >= 1; o >>= 1) {
                a0 += __shfl_xor(a0, o);
                a1 += __shfl_xor(a1, o);
                a2 += __shfl_xor(a2, o);
                a3 += __shfl_xor(a3, o);
            }
            if (lane == 0) {
                float t3[4] = { a0 + bb3[0], a1 + bb3[1], a2 + bb3[2], a3 + bb3[3] };
#pragma unroll
                for (int c = 0; c < 4; ++c) {
                    float rp = ref_in[(size_t)nq * 4 + c];
                    float xc = fminf(fmaxf(rp, 0.f), 1.f);
                    float invsig = logf(fmaxf(xc, 1e-5f) / fmaxf(1.f - xc, 1e-5f));
                    float rv = 1.f / (1.f + expf(-(t3[c] + invsig)));
                    refs[c] = rv;
                    ref_out[(size_t)nq * 4 + c] = rv;
                }
            }
        }
        __syncthreads();
    }

    float vr0 = svr[n * 2 + 0], vr1 = svr[n * 2 + 1];
    float rr0, rr1, rr2, rr3;
    if (IREF) {
        rr0 = refs[0]; rr1 = refs[1]; rr2 = refs[2]; rr3 = refs[3];
    } else {
        rr0 = ref_in[nq * 4 + 0]; rr1 = ref_in[nq * 4 + 1];
        rr2 = ref_in[nq * 4 + 2]; rr3 = ref_in[nq * 4 + 3];
    }
    float r0 = rr0 * vr0;
    float r1 = rr1 * vr1;
    float r2 = rr2 * vr0;
    float r3 = rr3 * vr1;

    const float* qrow = qoa + (size_t)nq * 96;

    float lgt[4];
    float mx = -1e30f;
#pragma unroll
    for (int p = 0; p < 4; ++p) {
        lgt[p] = qrow[64 + h * 4 + p];
        mx = fmaxf(mx, lgt[p]);
    }
    float ssum = 0.f;
#pragma unroll
    for (int p = 0; p < 4; ++p) { lgt[p] = expf(lgt[p] - mx); ssum += lgt[p]; }
    float sinv = 1.f / ssum;

    const unsigned short* vbase = value + (size_t)n * LEN * D + h * DH + dh;
    float acc = 0.f;

#pragma unroll
    for (int p = 0; p < NPTS; ++p) {
        float ox = qrow[h * 8 + p * 2 + 0];
        float oy = qrow[h * 8 + p * 2 + 1];
        float lx = r0 + ox * (1.f / NPTS) * r2 * 0.5f;
        float ly = r1 + oy * (1.f / NPTS) * r3 * 0.5f;
        float w  = lgt[p] * sinv;

        float x = lx * W_ - 0.5f;
        float y = ly * H_ - 0.5f;
        x = fminf(fmaxf(x, -1e4f), 1e4f);
        y = fminf(fmaxf(y, -1e4f), 1e4f);
        float x0f = floorf(x), y0f = floorf(y);
        float wx = x - x0f, wy = y - y0f;
        int x0 = (int)x0f, y0 = (int)y0f;

        float v00 = 0.f, v10 = 0.f, v01 = 0.f, v11 = 0.f;
        bool xin0 = (x0 >= 0 && x0 < W_);
        bool xin1 = (x0 + 1 >= 0 && x0 + 1 < W_);
        bool yin0 = (y0 >= 0 && y0 < H_);
        bool yin1 = (y0 + 1 >= 0 && y0 + 1 < H_);
        if (xin0 && yin0) v00 = bf2f(vbase[(size_t)(y0 * W_ + x0) * D]);
        if (xin1 && yin0) v10 = bf2f(vbase[(size_t)(y0 * W_ + x0 + 1) * D]);
        if (xin0 && yin1) v01 = bf2f(vbase[(size_t)((y0 + 1) * W_ + x0) * D]);
        if (xin1 && yin1) v11 = bf2f(vbase[(size_t)((y0 + 1) * W_ + x0 + 1) * D]);

        float bil = v00 * (1.f - wx) * (1.f - wy)
                  + v10 * wx * (1.f - wy)
                  + v01 * (1.f - wx) * wy
                  + v11 * wx * wy;
        acc += w * bil;
    }
    attn[(size_t)nq * D + h * DH + dh] = f2bf(acc);
}

// =====================================================================
// bbox final (LAST layer only)
// =====================================================================
__global__ __launch_bounds__(256) void bbox_kernel(
    const unsigned short* __restrict__ t2, const float* __restrict__ Wb3,
    const float* __restrict__ bb3, const float* __restrict__ ref_prev,
    float* __restrict__ ref_out)
{
    int row  = blockIdx.x * 4 + (threadIdx.x >> 6);
    int lane = threadIdx.x & 63;
    if (row >= MQ) return;

    float acc0 = 0.f, acc1 = 0.f, acc2 = 0.f, acc3 = 0.f;
    const unsigned short* tp = t2 + (size_t)row * D;
#pragma unroll
    for (int kk = 0; kk < D / 64; ++kk) {
        int k = lane + kk * 64;
        float tv = bf2f(tp[k]);
        const float4 wrow = *(const float4*)(Wb3 + (size_t)k * 4);
        acc0 = fmaf(tv, wrow.x, acc0);
        acc1 = fmaf(tv, wrow.y, acc1);
        acc2 = fmaf(tv, wrow.z, acc2);
        acc3 = fmaf(tv, wrow.w, acc3);
    }
#pragma unroll
    for (int o = 32; o >= 1; o >>= 1) {
        acc0 += __shfl_xor(acc0, o);
        acc1 += __shfl_xor(acc1, o);
        acc2 += __shfl_xor(acc2, o);
        acc3 += __shfl_xor(acc3, o);
    }
    if (lane == 0) {
        float t3[4] = { acc0 + bb3[0], acc1 + bb3[1], acc2 + bb3[2], acc3 + bb3[3] };
#pragma unroll
        for (int c = 0; c < 4; ++c) {
            float rp = ref_prev[(size_t)row * 4 + c];
            float xc = fminf(fmaxf(rp, 0.f), 1.f);
            float invsig = logf(fmaxf(xc, 1e-5f) / fmaxf(1.f - xc, 1e-5f));
            float sarg = t3[c] + invsig;
            ref_out[(size_t)row * 4 + c] = 1.f / (1.f + expf(-sarg));
        }
    }
}

// =====================================================================
// launcher
// =====================================================================
extern "C" void kernel_launch(void* const* d_in, const int* in_sizes, int n_in,
                              void* d_out, int out_size, void* d_ws, size_t ws_size,
                              hipStream_t stream)
{
    const float* tgt    = (const float*)d_in[0];
    const float* refpts = (const float*)d_in[1];
    const float* src    = (const float*)d_in[2];
    const float* svr    = (const float*)d_in[3];
    const float* qpos   = (const float*)d_in[4];
    const float* Wo     = (const float*)d_in[5];
    const float* bo     = (const float*)d_in[6];
    const float* Wa     = (const float*)d_in[7];
    const float* ba     = (const float*)d_in[8];
    const float* Wv     = (const float*)d_in[9];
    const float* bv     = (const float*)d_in[10];
    const float* Wout   = (const float*)d_in[11];
    const float* bout   = (const float*)d_in[12];
    const float* g1     = (const float*)d_in[13];
    const float* b1     = (const float*)d_in[14];
    const float* Wfc    = (const float*)d_in[15];
    const float* bfc    = (const float*)d_in[16];
    const float* Wproj  = (const float*)d_in[17];
    const float* bproj  = (const float*)d_in[18];
    const float* g2     = (const float*)d_in[19];
    const float* b2     = (const float*)d_in[20];
    const float* Wb1    = (const float*)d_in[21];
    const float* bb1    = (const float*)d_in[22];
    const float* Wb2    = (const float*)d_in[23];
    const float* bb2    = (const float*)d_in[24];
    const float* Wb3    = (const float*)d_in[25];
    const float* bb3    = (const float*)d_in[26];
    const unsigned char* mask = (const unsigned char*)d_in[29];

    float* outp  = (float*)d_out;
    float* inter     = outp;                             // (6, N, LQ, D)
    float* inter_ref = outp + (size_t)NLAYERS * MQ * D;  // (6, N, LQ, 4)

    // workspace carve-up
    char* wsb = (char*)d_ws;
    unsigned short* value    = (unsigned short*)wsb;  wsb += (size_t)MV * D * 2;  // 32 MiB
    unsigned short* src_bf16 = (unsigned short*)wsb;  wsb += (size_t)MV * D * 2;  // 32 MiB
    unsigned short* WvT      = (unsigned short*)wsb;  wsb += (size_t)NLAYERS * D * D * 2;
    unsigned short* WoaT     = (unsigned short*)wsb;  wsb += (size_t)NLAYERS * 128 * D * 2;
    unsigned short* WoutT    = (unsigned short*)wsb;  wsb += (size_t)NLAYERS * D * D * 2;
    unsigned short* WfcT     = (unsigned short*)wsb;  wsb += (size_t)NLAYERS * DFF * D * 2;
    unsigned short* WprojT   = (unsigned short*)wsb;  wsb += (size_t)NLAYERS * D * DFF * 2;
    unsigned short* Wb1T     = (unsigned short*)wsb;  wsb += (size_t)NLAYERS * D * D * 2;
    unsigned short* Wb2T     = (unsigned short*)wsb;  wsb += (size_t)NLAYERS * D * D * 2;
    unsigned short* hmlp     = (unsigned short*)wsb;  wsb += (size_t)MQ * DFF * 2;
    unsigned short* t1b      = (unsigned short*)wsb;  wsb += (size_t)MQ * D * 2;
    unsigned short* t2b      = (unsigned short*)wsb;  wsb += (size_t)MQ * D * 2;
    unsigned short* x1h      = (unsigned short*)wsb;  wsb += (size_t)MQ * D * 2;
    unsigned short* x2h      = (unsigned short*)wsb;  wsb += (size_t)MQ * D * 2;
    unsigned short* attnb    = (unsigned short*)wsb;  wsb += (size_t)MQ * D * 2;
    float* boa   = (float*)wsb;        wsb += (size_t)NLAYERS * 128 * 4;
    float* ws    = (float*)wsb;
    float* qoab  = ws;                 size_t o = (size_t)MQ * 96;
    float* tmpb  = ws + o;             o += (size_t)MQ * D;
    float* x1b   = ws + o;             o += (size_t)MQ * D;

    // ---- one-time conversions (6 dispatches) ----
    cvt_bf16_kernel<<<(MV * D / 8 + 255) / 256, 256, 0, stream>>>(src, src_bf16, MV * D / 8);
    {
        int t = NLAYERS * D * D;
        wt_cvt4_kernel<<<(t + 255) / 256, 256, 0, stream>>>(
            Wv, Wout, Wb1, Wb2, WvT, WoutT, Wb1T, Wb2T);
        t = NLAYERS * DFF * D;
        wt_cvt_kernel<<<(t + 255) / 256, 256, 0, stream>>>(Wfc,   WfcT,   D,   DFF, DFF, t);
        wt_cvt_kernel<<<(t + 255) / 256, 256, 0, stream>>>(Wproj, WprojT, DFF, D,   D,   t);
        t = NLAYERS * 128 * D;
        woat_kernel<<<(t + 255) / 256, 256, 0, stream>>>(Wo, Wa, WoaT);
        bias_concat_kernel<<<(NLAYERS * 128 + 255) / 256, 256, 0, stream>>>(bo, ba, boa);
    }

    // ---- layer-0 prologue: value(0) + qoa(0) ----
    fused_vq_kernel<false><<<VBLK + QBLK, 256, 0, stream>>>(
        src_bf16, WvT, bv, mask, value,
        tgt, qpos, WoaT, boa, qoab,
        nullptr, nullptr, nullptr, nullptr);

    for (int l = 0; l < NLAYERS; ++l) {
        const float* out_prev = (l == 0) ? tgt : inter + (size_t)(l - 1) * MQ * D;
        float* inter_l = inter + (size_t)l * MQ * D;

        // 1) sample (+ inline ref(l-1) refinement for l>=1) -> attn bf16
        if (l == 0) {
            sample_kernel<false><<<MQ, 256, 0, stream>>>(
                value, qoab, refpts, nullptr, nullptr, nullptr, nullptr, svr, attnb);
        } else {
            const float* ref_pp = (l == 1) ? refpts : inter_ref + (size_t)(l - 2) * MQ * 4;
            sample_kernel<true><<<MQ, 256, 0, stream>>>(
                value, qoab, ref_pp, t2b,
                Wb3 + (size_t)(l - 1) * D * 4, bb3 + (size_t)(l - 1) * 4,
                inter_ref + (size_t)(l - 1) * MQ * 4, svr, attnb);
        }

        // 2) attn(bf16) @ Wout + bout  (228 blocks, full async staging)
        gemm_q_mfma<true,false,false><<<dim3(4, MB), 256, 0, stream>>>(
            attnb, WoutT + (size_t)l * D * D, bout + (size_t)l * D, tmpb, MQ, D, D);

        // 3) x1 = LN(out_prev + tmp) -> fp32 + bf16
        ln_kernel<<<MQ / 4, 256, 0, stream>>>(
            out_prev, tmpb, g1 + (size_t)l * D, b1 + (size_t)l * D, x1b, x1h);

        // 4) h = relu(x1h @ Wfc + bfc) -> bf16  (64x64 tile, 912 blocks)
        gemm_q_mfma<true,true,true><<<dim3(DFF / 64, MB), 256, 0, stream>>>(
            x1h, WfcT + (size_t)l * DFF * D, bfc + (size_t)l * DFF, hmlp, MQ, DFF, D);

        // 5) proj: h @ Wproj + bproj  (228 blocks)
        gemm_q_mfma<true,false,false><<<dim3(4, MB), 256, 0, stream>>>(
            hmlp, WprojT + (size_t)l * D * DFF, bproj + (size_t)l * D, tmpb, MQ, D, DFF);

        // 6) x2 = LN(x1 + tmp) -> inter[l] fp32 + bf16
        ln_kernel<<<MQ / 4, 256, 0, stream>>>(
            x1b, tmpb, g2 + (size_t)l * D, b2 + (size_t)l * D, inter_l, x2h);

        // 7) b1(l) overlapped with value(l+1)+qoa(l+1)  [l<5]; plain b1 on last layer
        if (l < NLAYERS - 1) {
            fused_vq_kernel<true><<<VBLK + QBLK + BBLK, 256, 0, stream>>>(
                src_bf16, WvT + (size_t)(l + 1) * D * D, bv + (size_t)(l + 1) * D, mask, value,
                inter_l, qpos, WoaT + (size_t)(l + 1) * 128 * D, boa + (size_t)(l + 1) * 128, qoab,
                x2h, Wb1T + (size_t)l * D * D, bb1 + (size_t)l * D, t1b);
        } else {
            gemm_q_mfma<true,true,true><<<dim3(4, MB), 256, 0, stream>>>(
                x2h, Wb1T + (size_t)l * D * D, bb1 + (size_t)l * D, t1b, MQ, D, D);
        }

        // 8) t2 = relu(t1 @ Wb2 + bb2) -> bf16
        gemm_q_mfma<true,true,true><<<dim3(4, MB), 256, 0, stream>>>(
            t1b, Wb2T + (size_t)l * D * D, bb2 + (size_t)l * D, t2b, MQ, D, D);

        // 9) bbox only for the LAST layer
        if (l == NLAYERS - 1) {
            bbox_kernel<<<MQ / 4, 256, 0, stream>>>(
                t2b, Wb3 + (size_t)l * D * 4, bb3 + (size_t)l * 4,
                inter_ref + (size_t)(l - 1) * MQ * 4, inter_ref + (size_t)l * MQ * 4);
        }
    }
}

// Round 16
// 534.126 us; speedup vs baseline: 1.1391x; 1.0793x over previous
//
#include <hip/hip_runtime.h>
#include <hip/hip_bf16.h>
#include <math.h>

// ---- problem constants ----
constexpr int N_    = 4;
constexpr int LQ    = 900;
constexpr int D     = 256;
constexpr int HEADS = 8;
constexpr int DH    = 32;
constexpr int NPTS  = 4;
constexpr int LEN   = 16384;   // 128*128
constexpr int H_    = 128;
constexpr int W_    = 128;
constexpr int DFF   = 1024;
constexpr int NLAYERS = 6;
constexpr int MQ    = N_ * LQ;   // 3600
constexpr int MV    = N_ * LEN;  // 65536
constexpr int MB    = (MQ + 63) / 64;   // 57
constexpr int VBLK  = (D / 128) * (MV / 128);  // 1024 value blocks
constexpr int QBLK  = 2 * MB;                  // 114 qoa blocks
constexpr int BBLK  = 4 * MB;                  // 228 b1 blocks

typedef __attribute__((ext_vector_type(8))) short bf16x8;
typedef __attribute__((ext_vector_type(4))) float f32x4;

static __device__ __forceinline__ unsigned short f2bf(float v) {
    __hip_bfloat16 h = __float2bfloat16(v);
    return *(unsigned short*)&h;
}
static __device__ __forceinline__ float bf2f(unsigned short u) {
    __hip_bfloat16 h = *(__hip_bfloat16*)&u;
    return __bfloat162float(h);
}
static __device__ __forceinline__ bf16x8 pack8(const float* a, const float* b4) {
    union { bf16x8 v; unsigned short u[8]; } o;
    o.u[0] = f2bf(a[0]); o.u[1] = f2bf(a[1]); o.u[2] = f2bf(a[2]); o.u[3] = f2bf(a[3]);
    o.u[4] = f2bf(b4[0]); o.u[5] = f2bf(b4[1]); o.u[6] = f2bf(b4[2]); o.u[7] = f2bf(b4[3]);
    return o.v;
}

// async global->LDS, 16 B per lane (LDS dest wave-uniform base + lane*16)
static __device__ __forceinline__ void gload_lds16(const void* gaddr, void* laddr) {
    __builtin_amdgcn_global_load_lds(
        (const __attribute__((address_space(1))) unsigned int*)gaddr,
        (__attribute__((address_space(3))) unsigned int*)laddr,
        16, 0, 0);
}

// =====================================================================
// fp32 -> bf16 conversion (contiguous), n8 = count/8
// =====================================================================
__global__ __launch_bounds__(256) void cvt_bf16_kernel(
    const float* __restrict__ in, unsigned short* __restrict__ out, int n8)
{
    int i = blockIdx.x * 256 + threadIdx.x;
    if (i >= n8) return;
    float4 a = ((const float4*)in)[i * 2];
    float4 b = ((const float4*)in)[i * 2 + 1];
    float af[4] = {a.x, a.y, a.z, a.w}, bff[4] = {b.x, b.y, b.z, b.w};
    *(bf16x8*)(out + (size_t)i * 8) = pack8(af, bff);
}

// =====================================================================
// 4x D x D weight transpose+cvt in one dispatch (Wv, Wout, Wb1, Wb2)
// =====================================================================
__global__ __launch_bounds__(256) void wt_cvt4_kernel(
    const float* __restrict__ W0, const float* __restrict__ W1,
    const float* __restrict__ W2, const float* __restrict__ W3,
    unsigned short* __restrict__ T0, unsigned short* __restrict__ T1,
    unsigned short* __restrict__ T2, unsigned short* __restrict__ T3)
{
    int i = blockIdx.x * 256 + threadIdx.x;
    if (i >= NLAYERS * D * D) return;
    int k = i & (D - 1);
    int n = (i >> 8) & (D - 1);
    int l = i >> 16;
    size_t si = (size_t)l * D * D + (size_t)k * D + n;
    T0[i] = f2bf(W0[si]);
    T1[i] = f2bf(W1[si]);
    T2[i] = f2bf(W2[si]);
    T3[i] = f2bf(W3[si]);
}

// =====================================================================
// generic weight transpose+cvt: W (L,K,N) fp32 -> WT (L,Npad,K) bf16
// =====================================================================
__global__ __launch_bounds__(256) void wt_cvt_kernel(
    const float* __restrict__ W, unsigned short* __restrict__ WT,
    int K, int Nr, int Npad, int total)
{
    int i = blockIdx.x * 256 + threadIdx.x;
    if (i >= total) return;
    int k = i % K;
    int n = (i / K) % Npad;
    int l = i / (K * Npad);
    WT[i] = (n < Nr) ? f2bf(W[((size_t)l * K + k) * Nr + n]) : (unsigned short)0;
}

// =====================================================================
// WoaT: rows 0..63 = Wo^T (N=64), rows 64..95 = Wa^T (N=32), 96..127 = 0
// =====================================================================
__global__ __launch_bounds__(256) void woat_kernel(
    const float* __restrict__ Wo, const float* __restrict__ Wa,
    unsigned short* __restrict__ WoaT)
{
    int i = blockIdx.x * 256 + threadIdx.x;
    if (i >= NLAYERS * 128 * D) return;
    int k = i % D;
    int n = (i / D) & 127;
    int l = i / (D * 128);
    float v = 0.f;
    if (n < 64)      v = Wo[((size_t)l * D + k) * 64 + n];
    else if (n < 96) v = Wa[((size_t)l * D + k) * 32 + (n - 64)];
    WoaT[i] = f2bf(v);
}

__global__ __launch_bounds__(256) void bias_concat_kernel(
    const float* __restrict__ bo, const float* __restrict__ ba, float* __restrict__ boa)
{
    int i = blockIdx.x * 256 + threadIdx.x;
    if (i >= NLAYERS * 128) return;
    int n = i & 127;
    int l = i >> 7;
    float v = 0.f;
    if (n < 64)      v = bo[l * 64 + n];
    else if (n < 96) v = ba[l * 32 + (n - 64)];
    boa[i] = v;
}

// =====================================================================
// 3-way fused dispatch (r12-validated):
//   [0, VBLK):           value GEMM layer l+1 (128x128, XCD pairing)
//   [VBLK, VBLK+QBLK):   qoa GEMM layer l+1 (64x64, fused add)
//   [VBLK+QBLK, +BBLK):  b1 GEMM layer l (64x64, bf16 A, relu, bf16 out)
// =====================================================================
template<bool HAS_B1>
__global__ __launch_bounds__(256) void fused_vq_kernel(
    const unsigned short* __restrict__ A, const unsigned short* __restrict__ Bt,
    const float* __restrict__ bias, const unsigned char* __restrict__ mask,
    unsigned short* __restrict__ C,
    const float* __restrict__ Aq, const float* __restrict__ A2q,
    const unsigned short* __restrict__ Btq, const float* __restrict__ biasq,
    float* __restrict__ Cq,
    const unsigned short* __restrict__ Ab1, const unsigned short* __restrict__ Btb1,
    const float* __restrict__ biasb1, unsigned short* __restrict__ Cb1)
{
    __shared__ unsigned short Asm[128 * 64];
    __shared__ unsigned short Bsm[128 * 64];

    const int bid  = blockIdx.x;
    const int tid  = threadIdx.x;
    const int wave = tid >> 6;
    const int lane = tid & 63;
    const int lg   = lane >> 4;
    const int lr   = lane & 15;

    if (bid < VBLK) {
        const int y  = (bid >> 4) * 8 + (bid & 7);
        const int x  = (bid >> 3) & 1;
        const int m0 = y * 128;
        const int n0 = x * 128;
        const int wr = wave >> 1;
        const int wc = wave & 1;

        f32x4 acc[4][4];
#pragma unroll
        for (int i = 0; i < 4; ++i)
#pragma unroll
            for (int j = 0; j < 4; ++j) acc[i][j] = (f32x4){0.f, 0.f, 0.f, 0.f};

        for (int k0 = 0; k0 < D; k0 += 64) {
#pragma unroll
            for (int it = 0; it < 4; ++it) {
                int c   = tid + it * 256;
                int row = c >> 3;
                int kch = (c & 7) ^ (row & 7);
                unsigned ldsoff = (unsigned)(it * 256 + wave * 64) * 16;
                gload_lds16(A  + (size_t)(m0 + row) * D + k0 + kch * 8, (char*)Asm + ldsoff);
                gload_lds16(Bt + (size_t)(n0 + row) * D + k0 + kch * 8, (char*)Bsm + ldsoff);
            }
            __syncthreads();

            bf16x8 af[4][2], bfr[4][2];
#pragma unroll
            for (int i = 0; i < 4; ++i) {
#pragma unroll
                for (int kk = 0; kk < 2; ++kk) {
                    int arow = wr * 64 + i * 16 + lr;
                    af[i][kk]  = *(const bf16x8*)((char*)Asm + arow * 128 + 16 * ((kk * 4 + lg) ^ (arow & 7)));
                    int brow = wc * 64 + i * 16 + lr;
                    bfr[i][kk] = *(const bf16x8*)((char*)Bsm + brow * 128 + 16 * ((kk * 4 + lg) ^ (brow & 7)));
                }
            }
#pragma unroll
            for (int kk = 0; kk < 2; ++kk)
#pragma unroll
                for (int i = 0; i < 4; ++i)
#pragma unroll
                    for (int j = 0; j < 4; ++j)
                        acc[i][j] = __builtin_amdgcn_mfma_f32_16x16x32_bf16(
                            af[i][kk], bfr[j][kk], acc[i][j], 0, 0, 0);
            __syncthreads();
        }

#pragma unroll
        for (int i = 0; i < 4; ++i) {
            int mbase = m0 + wr * 64 + i * 16 + lg * 4;
#pragma unroll
            for (int j = 0; j < 4; ++j) {
                int n = n0 + wc * 64 + j * 16 + lr;
                float bn = bias[n];
#pragma unroll
                for (int r = 0; r < 4; ++r) {
                    int m = mbase + r;
                    float v = acc[i][j][r] + bn;
                    if (mask[m]) v = 0.f;
                    C[(size_t)m * D + n] = f2bf(v);
                }
            }
        }
    } else if (bid < VBLK + QBLK) {
        const int qb = bid - VBLK;
        const int n0 = (qb & 1) * 64;
        const int m0 = (qb >> 1) * 64;
        const int wr = wave >> 1;
        const int wc = wave & 1;

        f32x4 acc[2][2];
#pragma unroll
        for (int i = 0; i < 2; ++i)
#pragma unroll
            for (int j = 0; j < 2; ++j) acc[i][j] = (f32x4){0.f, 0.f, 0.f, 0.f};

        for (int k0 = 0; k0 < D; k0 += 64) {
#pragma unroll
            for (int it = 0; it < 2; ++it) {
                int c   = tid + it * 256;
                int row = c >> 3;
                int kc  = c & 7;
                int kch = kc ^ (row & 7);
                unsigned ldsoff = (unsigned)(it * 256 + wave * 64) * 16;
                gload_lds16(Btq + (size_t)(n0 + row) * D + k0 + kch * 8, (char*)Bsm + ldsoff);
                int gm = m0 + row;
                bf16x8 v = (bf16x8){0,0,0,0,0,0,0,0};
                if (gm < MQ) {
                    const float* ap = Aq  + (size_t)gm * D + k0 + kc * 8;
                    const float* qp = A2q + (size_t)gm * D + k0 + kc * 8;
                    float4 a = *(const float4*)ap;
                    float4 b = *(const float4*)(ap + 4);
                    float4 qa = *(const float4*)qp;
                    float4 qb4 = *(const float4*)(qp + 4);
                    a.x += qa.x; a.y += qa.y; a.z += qa.z; a.w += qa.w;
                    b.x += qb4.x; b.y += qb4.y; b.z += qb4.z; b.w += qb4.w;
                    float af_[4] = {a.x, a.y, a.z, a.w}, bf_[4] = {b.x, b.y, b.z, b.w};
                    v = pack8(af_, bf_);
                }
                *(bf16x8*)((char*)Asm + row * 128 + 16 * (kc ^ (row & 7))) = v;
            }
            __syncthreads();

            bf16x8 af[2][2], bfr[2][2];
#pragma unroll
            for (int i = 0; i < 2; ++i) {
#pragma unroll
                for (int kk = 0; kk < 2; ++kk) {
                    int arow = wr * 32 + i * 16 + lr;
                    af[i][kk]  = *(const bf16x8*)((char*)Asm + arow * 128 + 16 * ((kk * 4 + lg) ^ (arow & 7)));
                    int brow = wc * 32 + i * 16 + lr;
                    bfr[i][kk] = *(const bf16x8*)((char*)Bsm + brow * 128 + 16 * ((kk * 4 + lg) ^ (brow & 7)));
                }
            }
#pragma unroll
            for (int kk = 0; kk < 2; ++kk)
#pragma unroll
                for (int i = 0; i < 2; ++i)
#pragma unroll
                    for (int j = 0; j < 2; ++j)
                        acc[i][j] = __builtin_amdgcn_mfma_f32_16x16x32_bf16(
                            af[i][kk], bfr[j][kk], acc[i][j], 0, 0, 0);
            __syncthreads();
        }

#pragma unroll
        for (int i = 0; i < 2; ++i) {
            int mbase = m0 + wr * 32 + i * 16 + lg * 4;
#pragma unroll
            for (int j = 0; j < 2; ++j) {
                int n = n0 + wc * 32 + j * 16 + lr;
                if (n >= 96) continue;
                float bn = biasq[n];
#pragma unroll
                for (int r = 0; r < 4; ++r) {
                    int m = mbase + r;
                    if (m >= MQ) continue;
                    Cq[(size_t)m * 96 + n] = acc[i][j][r] + bn;
                }
            }
        }
    } else if (HAS_B1) {
        const int bb = bid - VBLK - QBLK;
        const int n0 = (bb & 3) * 64;
        const int m0 = (bb >> 2) * 64;
        const int wr = wave >> 1;
        const int wc = wave & 1;

        f32x4 acc[2][2];
#pragma unroll
        for (int i = 0; i < 2; ++i)
#pragma unroll
            for (int j = 0; j < 2; ++j) acc[i][j] = (f32x4){0.f, 0.f, 0.f, 0.f};

        for (int k0 = 0; k0 < D; k0 += 64) {
#pragma unroll
            for (int it = 0; it < 2; ++it) {
                int c   = tid + it * 256;
                int row = c >> 3;
                int kch = (c & 7) ^ (row & 7);
                unsigned ldsoff = (unsigned)(it * 256 + wave * 64) * 16;
                gload_lds16(Btb1 + (size_t)(n0 + row) * D + k0 + kch * 8, (char*)Bsm + ldsoff);
                gload_lds16(Ab1  + (size_t)(m0 + row) * D + k0 + kch * 8, (char*)Asm + ldsoff);
            }
            __syncthreads();

            bf16x8 af[2][2], bfr[2][2];
#pragma unroll
            for (int i = 0; i < 2; ++i) {
#pragma unroll
                for (int kk = 0; kk < 2; ++kk) {
                    int arow = wr * 32 + i * 16 + lr;
                    af[i][kk]  = *(const bf16x8*)((char*)Asm + arow * 128 + 16 * ((kk * 4 + lg) ^ (arow & 7)));
                    int brow = wc * 32 + i * 16 + lr;
                    bfr[i][kk] = *(const bf16x8*)((char*)Bsm + brow * 128 + 16 * ((kk * 4 + lg) ^ (brow & 7)));
                }
            }
#pragma unroll
            for (int kk = 0; kk < 2; ++kk)
#pragma unroll
                for (int i = 0; i < 2; ++i)
#pragma unroll
                    for (int j = 0; j < 2; ++j)
                        acc[i][j] = __builtin_amdgcn_mfma_f32_16x16x32_bf16(
                            af[i][kk], bfr[j][kk], acc[i][j], 0, 0, 0);
            __syncthreads();
        }

#pragma unroll
        for (int i = 0; i < 2; ++i) {
            int mbase = m0 + wr * 32 + i * 16 + lg * 4;
#pragma unroll
            for (int j = 0; j < 2; ++j) {
                int n = n0 + wc * 32 + j * 16 + lr;
#pragma unroll
                for (int r = 0; r < 4; ++r) {
                    int m = mbase + r;
                    if (m >= MQ) continue;
                    float v = fmaxf(acc[i][j][r] + biasb1[n], 0.f);
                    Cb1[(size_t)m * D + n] = f2bf(v);
                }
            }
        }
    }
}

// =====================================================================
// MFMA query GEMM: C[M,Nreal] = A[M,K] @ Bt^T + bias (+relu). (r10-validated)
// =====================================================================
template<bool ABF16, bool RELU, bool OUTBF16>
__global__ __launch_bounds__(256) void gemm_q_mfma(
    const void* __restrict__ Av,
    const unsigned short* __restrict__ Bt, const float* __restrict__ bias,
    void* __restrict__ Cv, int M, int Nreal, int K)
{
    __shared__ unsigned short Asm[64 * 64];
    __shared__ unsigned short Bsm[64 * 64];

    const int tid  = threadIdx.x;
    const int m0   = blockIdx.y * 64;
    const int n0   = blockIdx.x * 64;
    const int wave = tid >> 6;
    const int lane = tid & 63;
    const int wr   = wave >> 1;
    const int wc   = wave & 1;
    const int lg   = lane >> 4;
    const int lr   = lane & 15;

    f32x4 acc[2][2];
#pragma unroll
    for (int i = 0; i < 2; ++i)
#pragma unroll
        for (int j = 0; j < 2; ++j) acc[i][j] = (f32x4){0.f, 0.f, 0.f, 0.f};

    for (int k0 = 0; k0 < K; k0 += 64) {
#pragma unroll
        for (int it = 0; it < 2; ++it) {
            int c   = tid + it * 256;
            int row = c >> 3;
            int kch = (c & 7) ^ (row & 7);
            unsigned ldsoff = (unsigned)(it * 256 + wave * 64) * 16;
            gload_lds16(Bt + (size_t)(n0 + row) * K + k0 + kch * 8, (char*)Bsm + ldsoff);
            if (ABF16) {
                gload_lds16((const unsigned short*)Av + (size_t)(m0 + row) * K + k0 + kch * 8,
                            (char*)Asm + ldsoff);
            } else {
                int kc = c & 7;
                int gm = m0 + row;
                bf16x8 v = (bf16x8){0,0,0,0,0,0,0,0};
                if (gm < M) {
                    const float* ap = (const float*)Av + (size_t)gm * K + k0 + kc * 8;
                    float4 a = *(const float4*)ap;
                    float4 b = *(const float4*)(ap + 4);
                    float af_[4] = {a.x, a.y, a.z, a.w}, bf_[4] = {b.x, b.y, b.z, b.w};
                    v = pack8(af_, bf_);
                }
                *(bf16x8*)((char*)Asm + row * 128 + 16 * (kc ^ (row & 7))) = v;
            }
        }
        __syncthreads();

        bf16x8 af[2][2], bfr[2][2];
#pragma unroll
        for (int i = 0; i < 2; ++i) {
#pragma unroll
            for (int kk = 0; kk < 2; ++kk) {
                int arow = wr * 32 + i * 16 + lr;
                af[i][kk]  = *(const bf16x8*)((char*)Asm + arow * 128 + 16 * ((kk * 4 + lg) ^ (arow & 7)));
                int brow = wc * 32 + i * 16 + lr;
                bfr[i][kk] = *(const bf16x8*)((char*)Bsm + brow * 128 + 16 * ((kk * 4 + lg) ^ (brow & 7)));
            }
        }
#pragma unroll
        for (int kk = 0; kk < 2; ++kk)
#pragma unroll
            for (int i = 0; i < 2; ++i)
#pragma unroll
                for (int j = 0; j < 2; ++j)
                    acc[i][j] = __builtin_amdgcn_mfma_f32_16x16x32_bf16(
                        af[i][kk], bfr[j][kk], acc[i][j], 0, 0, 0);
        __syncthreads();
    }

#pragma unroll
    for (int i = 0; i < 2; ++i) {
        int mbase = m0 + wr * 32 + i * 16 + lg * 4;
#pragma unroll
        for (int j = 0; j < 2; ++j) {
            int n = n0 + wc * 32 + j * 16 + lr;
            if (n >= Nreal) continue;
            float bn = bias[n];
#pragma unroll
            for (int r = 0; r < 4; ++r) {
                int m = mbase + r;
                if (m >= M) continue;
                float v = acc[i][j][r] + bn;
                if (RELU) v = fmaxf(v, 0.f);
                if (OUTBF16) ((unsigned short*)Cv)[(size_t)m * Nreal + n] = f2bf(v);
                else         ((float*)Cv)[(size_t)m * Nreal + n] = v;
            }
        }
    }
}

// =====================================================================
// LN over D=256: out = LN(a+b)*g + be; bf16 copy outh.
// =====================================================================
__global__ __launch_bounds__(256) void ln_kernel(
    const float* __restrict__ a, const float* __restrict__ b,
    const float* __restrict__ g, const float* __restrict__ be,
    float* __restrict__ out, unsigned short* __restrict__ outh)
{
    int row  = blockIdx.x * 4 + (threadIdx.x >> 6);
    int lane = threadIdx.x & 63;
    if (row >= MQ) return;

    const float4 va = *(const float4*)(a + (size_t)row * D + lane * 4);
    const float4 vb = *(const float4*)(b + (size_t)row * D + lane * 4);
    float x[4] = { va.x + vb.x, va.y + vb.y, va.z + vb.z, va.w + vb.w };

    float s = x[0] + x[1] + x[2] + x[3];
    float s2 = x[0]*x[0] + x[1]*x[1] + x[2]*x[2] + x[3]*x[3];
#pragma unroll
    for (int o = 32; o >= 1; o >>= 1) {
        s  += __shfl_xor(s,  o);
        s2 += __shfl_xor(s2, o);
    }
    float mean = s * (1.f / D);
    float var  = s2 * (1.f / D) - mean * mean;
    float rinv = rsqrtf(var + 1e-5f);

    float4 vg = *(const float4*)(g  + lane * 4);
    float4 vbe = *(const float4*)(be + lane * 4);
    float4 vo;
    vo.x = (x[0] - mean) * rinv * vg.x + vbe.x;
    vo.y = (x[1] - mean) * rinv * vg.y + vbe.y;
    vo.z = (x[2] - mean) * rinv * vg.z + vbe.z;
    vo.w = (x[3] - mean) * rinv * vg.w + vbe.w;
    *(float4*)(out + (size_t)row * D + lane * 4) = vo;

    ushort4 ho;
    ho.x = f2bf(vo.x); ho.y = f2bf(vo.y); ho.z = f2bf(vo.z); ho.w = f2bf(vo.w);
    *(ushort4*)(outh + (size_t)row * D + lane * 4) = ho;
}

// =====================================================================
// sample kernel, 128 threads/block (2 waves), one query per block.
// Each thread owns an element PAIR (u32 = 2 bf16): h = tid>>4, e0 = (tid&15)*2.
// Halves gather transaction count vs u16-per-thread. Optional inline
// bbox-refinement of the previous layer (wave 0). attn written as bf16 (u32).
// =====================================================================
template<bool IREF>
__global__ __launch_bounds__(128) void sample_kernel(
    const unsigned short* __restrict__ value, const float* __restrict__ qoa,
    const float* __restrict__ ref_in,
    const unsigned short* __restrict__ t2,
    const float* __restrict__ Wb3, const float* __restrict__ bb3,
    float* __restrict__ ref_out,
    const float* __restrict__ svr,
    unsigned short* __restrict__ attn)
{
    __shared__ float refs[4];

    int nq = blockIdx.x;
    int h  = threadIdx.x >> 4;          // 0..7
    int e0 = (threadIdx.x & 15) * 2;    // 0,2,..,30
    int n  = nq / LQ;

    if (IREF) {
        if (threadIdx.x < 64) {
            int lane = threadIdx.x;
            float a0 = 0.f, a1 = 0.f, a2 = 0.f, a3 = 0.f;
            const unsigned short* tp = t2 + (size_t)nq * D;
#pragma unroll
            for (int kk = 0; kk < D / 64; ++kk) {
                int k = lane + kk * 64;
                float tv = bf2f(tp[k]);
                const float4 wrow = *(const float4*)(Wb3 + (size_t)k * 4);
                a0 = fmaf(tv, wrow.x, a0);
                a1 = fmaf(tv, wrow.y, a1);
                a2 = fmaf(tv, wrow.z, a2);
                a3 = fmaf(tv, wrow.w, a3);
            }
#pragma unroll
            for (int o = 32; o >= 1; o >>= 1) {
                a0 += __shfl_xor(a0, o);
                a1 += __shfl_xor(a1, o);
                a2 += __shfl_xor(a2, o);
                a3 += __shfl_xor(a3, o);
            }
            if (lane == 0) {
                float t3[4] = { a0 + bb3[0], a1 + bb3[1], a2 + bb3[2], a3 + bb3[3] };
#pragma unroll
                for (int c = 0; c < 4; ++c) {
                    float rp = ref_in[(size_t)nq * 4 + c];
                    float xc = fminf(fmaxf(rp, 0.f), 1.f);
                    float invsig = logf(fmaxf(xc, 1e-5f) / fmaxf(1.f - xc, 1e-5f));
                    float rv = 1.f / (1.f + expf(-(t3[c] + invsig)));
                    refs[c] = rv;
                    ref_out[(size_t)nq * 4 + c] = rv;
                }
            }
        }
        __syncthreads();
    }

    float vr0 = svr[n * 2 + 0], vr1 = svr[n * 2 + 1];
    float rr0, rr1, rr2, rr3;
    if (IREF) {
        rr0 = refs[0]; rr1 = refs[1]; rr2 = refs[2]; rr3 = refs[3];
    } else {
        rr0 = ref_in[nq * 4 + 0]; rr1 = ref_in[nq * 4 + 1];
        rr2 = ref_in[nq * 4 + 2]; rr3 = ref_in[nq * 4 + 3];
    }
    float r0 = rr0 * vr0;
    float r1 = rr1 * vr1;
    float r2 = rr2 * vr0;
    float r3 = rr3 * vr1;

    const float* qrow = qoa + (size_t)nq * 96;

    float lgt[4];
    float mx = -1e30f;
#pragma unroll
    for (int p = 0; p < 4; ++p) {
        lgt[p] = qrow[64 + h * 4 + p];
        mx = fmaxf(mx, lgt[p]);
    }
    float ssum = 0.f;
#pragma unroll
    for (int p = 0; p < 4; ++p) { lgt[p] = expf(lgt[p] - mx); ssum += lgt[p]; }
    float sinv = 1.f / ssum;

    const unsigned short* vbase = value + (size_t)n * LEN * D + h * DH + e0;
    float acc0 = 0.f, acc1 = 0.f;

#pragma unroll
    for (int p = 0; p < NPTS; ++p) {
        float ox = qrow[h * 8 + p * 2 + 0];
        float oy = qrow[h * 8 + p * 2 + 1];
        float lx = r0 + ox * (1.f / NPTS) * r2 * 0.5f;
        float ly = r1 + oy * (1.f / NPTS) * r3 * 0.5f;
        float w  = lgt[p] * sinv;

        float x = lx * W_ - 0.5f;
        float y = ly * H_ - 0.5f;
        x = fminf(fmaxf(x, -1e4f), 1e4f);
        y = fminf(fmaxf(y, -1e4f), 1e4f);
        float x0f = floorf(x), y0f = floorf(y);
        float wx = x - x0f, wy = y - y0f;
        int x0 = (int)x0f, y0 = (int)y0f;

        float cw[4] = { (1.f - wx) * (1.f - wy), wx * (1.f - wy),
                        (1.f - wx) * wy,         wx * wy };
        int xs[4] = { x0, x0 + 1, x0,     x0 + 1 };
        int ys[4] = { y0, y0,     y0 + 1, y0 + 1 };

#pragma unroll
        for (int c = 0; c < 4; ++c) {
            int xi = xs[c], yi = ys[c];
            bool ok = (xi >= 0) & (xi < W_) & (yi >= 0) & (yi < H_);
            if (!ok) continue;
            unsigned pv = *(const unsigned*)(vbase + (size_t)(yi * W_ + xi) * D);
            float coeff = w * cw[c];
            acc0 = fmaf(coeff, bf2f((unsigned short)(pv & 0xffff)), acc0);
            acc1 = fmaf(coeff, bf2f((unsigned short)(pv >> 16)),    acc1);
        }
    }
    unsigned outp = (unsigned)f2bf(acc0) | ((unsigned)f2bf(acc1) << 16);
    *(unsigned*)(attn + (size_t)nq * D + h * DH + e0) = outp;
}

// =====================================================================
// bbox final (LAST layer only)
// =====================================================================
__global__ __launch_bounds__(256) void bbox_kernel(
    const unsigned short* __restrict__ t2, const float* __restrict__ Wb3,
    const float* __restrict__ bb3, const float* __restrict__ ref_prev,
    float* __restrict__ ref_out)
{
    int row  = blockIdx.x * 4 + (threadIdx.x >> 6);
    int lane = threadIdx.x & 63;
    if (row >= MQ) return;

    float acc0 = 0.f, acc1 = 0.f, acc2 = 0.f, acc3 = 0.f;
    const unsigned short* tp = t2 + (size_t)row * D;
#pragma unroll
    for (int kk = 0; kk < D / 64; ++kk) {
        int k = lane + kk * 64;
        float tv = bf2f(tp[k]);
        const float4 wrow = *(const float4*)(Wb3 + (size_t)k * 4);
        acc0 = fmaf(tv, wrow.x, acc0);
        acc1 = fmaf(tv, wrow.y, acc1);
        acc2 = fmaf(tv, wrow.z, acc2);
        acc3 = fmaf(tv, wrow.w, acc3);
    }
#pragma unroll
    for (int o = 32; o >= 1; o >>= 1) {
        acc0 += __shfl_xor(acc0, o);
        acc1 += __shfl_xor(acc1, o);
        acc2 += __shfl_xor(acc2, o);
        acc3 += __shfl_xor(acc3, o);
    }
    if (lane == 0) {
        float t3[4] = { acc0 + bb3[0], acc1 + bb3[1], acc2 + bb3[2], acc3 + bb3[3] };
#pragma unroll
        for (int c = 0; c < 4; ++c) {
            float rp = ref_prev[(size_t)row * 4 + c];
            float xc = fminf(fmaxf(rp, 0.f), 1.f);
            float invsig = logf(fmaxf(xc, 1e-5f) / fmaxf(1.f - xc, 1e-5f));
            float sarg = t3[c] + invsig;
            ref_out[(size_t)row * 4 + c] = 1.f / (1.f + expf(-sarg));
        }
    }
}

// =====================================================================
// launcher
// =====================================================================
extern "C" void kernel_launch(void* const* d_in, const int* in_sizes, int n_in,
                              void* d_out, int out_size, void* d_ws, size_t ws_size,
                              hipStream_t stream)
{
    const float* tgt    = (const float*)d_in[0];
    const float* refpts = (const float*)d_in[1];
    const float* src    = (const float*)d_in[2];
    const float* svr    = (const float*)d_in[3];
    const float* qpos   = (const float*)d_in[4];
    const float* Wo     = (const float*)d_in[5];
    const float* bo     = (const float*)d_in[6];
    const float* Wa     = (const float*)d_in[7];
    const float* ba     = (const float*)d_in[8];
    const float* Wv     = (const float*)d_in[9];
    const float* bv     = (const float*)d_in[10];
    const float* Wout   = (const float*)d_in[11];
    const float* bout   = (const float*)d_in[12];
    const float* g1     = (const float*)d_in[13];
    const float* b1     = (const float*)d_in[14];
    const float* Wfc    = (const float*)d_in[15];
    const float* bfc    = (const float*)d_in[16];
    const float* Wproj  = (const float*)d_in[17];
    const float* bproj  = (const float*)d_in[18];
    const float* g2     = (const float*)d_in[19];
    const float* b2     = (const float*)d_in[20];
    const float* Wb1    = (const float*)d_in[21];
    const float* bb1    = (const float*)d_in[22];
    const float* Wb2    = (const float*)d_in[23];
    const float* bb2    = (const float*)d_in[24];
    const float* Wb3    = (const float*)d_in[25];
    const float* bb3    = (const float*)d_in[26];
    const unsigned char* mask = (const unsigned char*)d_in[29];

    float* outp  = (float*)d_out;
    float* inter     = outp;                             // (6, N, LQ, D)
    float* inter_ref = outp + (size_t)NLAYERS * MQ * D;  // (6, N, LQ, 4)

    // workspace carve-up
    char* wsb = (char*)d_ws;
    unsigned short* value    = (unsigned short*)wsb;  wsb += (size_t)MV * D * 2;  // 32 MiB
    unsigned short* src_bf16 = (unsigned short*)wsb;  wsb += (size_t)MV * D * 2;  // 32 MiB
    unsigned short* WvT      = (unsigned short*)wsb;  wsb += (size_t)NLAYERS * D * D * 2;
    unsigned short* WoaT     = (unsigned short*)wsb;  wsb += (size_t)NLAYERS * 128 * D * 2;
    unsigned short* WoutT    = (unsigned short*)wsb;  wsb += (size_t)NLAYERS * D * D * 2;
    unsigned short* WfcT     = (unsigned short*)wsb;  wsb += (size_t)NLAYERS * DFF * D * 2;
    unsigned short* WprojT   = (unsigned short*)wsb;  wsb += (size_t)NLAYERS * D * DFF * 2;
    unsigned short* Wb1T     = (unsigned short*)wsb;  wsb += (size_t)NLAYERS * D * D * 2;
    unsigned short* Wb2T     = (unsigned short*)wsb;  wsb += (size_t)NLAYERS * D * D * 2;
    unsigned short* hmlp     = (unsigned short*)wsb;  wsb += (size_t)MQ * DFF * 2;
    unsigned short* t1b      = (unsigned short*)wsb;  wsb += (size_t)MQ * D * 2;
    unsigned short* t2b      = (unsigned short*)wsb;  wsb += (size_t)MQ * D * 2;
    unsigned short* x1h      = (unsigned short*)wsb;  wsb += (size_t)MQ * D * 2;
    unsigned short* x2h      = (unsigned short*)wsb;  wsb += (size_t)MQ * D * 2;
    unsigned short* attnb    = (unsigned short*)wsb;  wsb += (size_t)MQ * D * 2;
    float* boa   = (float*)wsb;        wsb += (size_t)NLAYERS * 128 * 4;
    float* ws    = (float*)wsb;
    float* qoab  = ws;                 size_t o = (size_t)MQ * 96;
    float* tmpb  = ws + o;             o += (size_t)MQ * D;
    float* x1b   = ws + o;             o += (size_t)MQ * D;

    // ---- one-time conversions (6 dispatches) ----
    cvt_bf16_kernel<<<(MV * D / 8 + 255) / 256, 256, 0, stream>>>(src, src_bf16, MV * D / 8);
    {
        int t = NLAYERS * D * D;
        wt_cvt4_kernel<<<(t + 255) / 256, 256, 0, stream>>>(
            Wv, Wout, Wb1, Wb2, WvT, WoutT, Wb1T, Wb2T);
        t = NLAYERS * DFF * D;
        wt_cvt_kernel<<<(t + 255) / 256, 256, 0, stream>>>(Wfc,   WfcT,   D,   DFF, DFF, t);
        wt_cvt_kernel<<<(t + 255) / 256, 256, 0, stream>>>(Wproj, WprojT, DFF, D,   D,   t);
        t = NLAYERS * 128 * D;
        woat_kernel<<<(t + 255) / 256, 256, 0, stream>>>(Wo, Wa, WoaT);
        bias_concat_kernel<<<(NLAYERS * 128 + 255) / 256, 256, 0, stream>>>(bo, ba, boa);
    }

    // ---- layer-0 prologue: value(0) + qoa(0) ----
    fused_vq_kernel<false><<<VBLK + QBLK, 256, 0, stream>>>(
        src_bf16, WvT, bv, mask, value,
        tgt, qpos, WoaT, boa, qoab,
        nullptr, nullptr, nullptr, nullptr);

    for (int l = 0; l < NLAYERS; ++l) {
        const float* out_prev = (l == 0) ? tgt : inter + (size_t)(l - 1) * MQ * D;
        float* inter_l = inter + (size_t)l * MQ * D;

        // 1) sample (+ inline ref(l-1) refinement for l>=1) -> attn bf16
        if (l == 0) {
            sample_kernel<false><<<MQ, 128, 0, stream>>>(
                value, qoab, refpts, nullptr, nullptr, nullptr, nullptr, svr, attnb);
        } else {
            const float* ref_pp = (l == 1) ? refpts : inter_ref + (size_t)(l - 2) * MQ * 4;
            sample_kernel<true><<<MQ, 128, 0, stream>>>(
                value, qoab, ref_pp, t2b,
                Wb3 + (size_t)(l - 1) * D * 4, bb3 + (size_t)(l - 1) * 4,
                inter_ref + (size_t)(l - 1) * MQ * 4, svr, attnb);
        }

        // 2) attn(bf16) @ Wout + bout  (228 blocks, full async staging)
        gemm_q_mfma<true,false,false><<<dim3(4, MB), 256, 0, stream>>>(
            attnb, WoutT + (size_t)l * D * D, bout + (size_t)l * D, tmpb, MQ, D, D);

        // 3) x1 = LN(out_prev + tmp) -> fp32 + bf16
        ln_kernel<<<MQ / 4, 256, 0, stream>>>(
            out_prev, tmpb, g1 + (size_t)l * D, b1 + (size_t)l * D, x1b, x1h);

        // 4) h = relu(x1h @ Wfc + bfc) -> bf16  (64x64 tile, 912 blocks)
        gemm_q_mfma<true,true,true><<<dim3(DFF / 64, MB), 256, 0, stream>>>(
            x1h, WfcT + (size_t)l * DFF * D, bfc + (size_t)l * DFF, hmlp, MQ, DFF, D);

        // 5) proj: h @ Wproj + bproj  (228 blocks)
        gemm_q_mfma<true,false,false><<<dim3(4, MB), 256, 0, stream>>>(
            hmlp, WprojT + (size_t)l * D * DFF, bproj + (size_t)l * D, tmpb, MQ, D, DFF);

        // 6) x2 = LN(x1 + tmp) -> inter[l] fp32 + bf16
        ln_kernel<<<MQ / 4, 256, 0, stream>>>(
            x1b, tmpb, g2 + (size_t)l * D, b2 + (size_t)l * D, inter_l, x2h);

        // 7) b1(l) overlapped with value(l+1)+qoa(l+1)  [l<5]; plain b1 on last layer
        if (l < NLAYERS - 1) {
            fused_vq_kernel<true><<<VBLK + QBLK + BBLK, 256, 0, stream>>>(
                src_bf16, WvT + (size_t)(l + 1) * D * D, bv + (size_t)(l + 1) * D, mask, value,
                inter_l, qpos, WoaT + (size_t)(l + 1) * 128 * D, boa + (size_t)(l + 1) * 128, qoab,
                x2h, Wb1T + (size_t)l * D * D, bb1 + (size_t)l * D, t1b);
        } else {
            gemm_q_mfma<true,true,true><<<dim3(4, MB), 256, 0, stream>>>(
                x2h, Wb1T + (size_t)l * D * D, bb1 + (size_t)l * D, t1b, MQ, D, D);
        }

        // 8) t2 = relu(t1 @ Wb2 + bb2) -> bf16
        gemm_q_mfma<true,true,true><<<dim3(4, MB), 256, 0, stream>>>(
            t1b, Wb2T + (size_t)l * D * D, bb2 + (size_t)l * D, t2b, MQ, D, D);

        // 9) bbox only for the LAST layer
        if (l == NLAYERS - 1) {
            bbox_kernel<<<MQ / 4, 256, 0, stream>>>(
                t2b, Wb3 + (size_t)l * D * 4, bb3 + (size_t)l * 4,
                inter_ref + (size_t)(l - 1) * MQ * 4, inter_ref + (size_t)l * MQ * 4);
        }
    }
}

// Round 17
// 532.652 us; speedup vs baseline: 1.1422x; 1.0028x over previous
//
#include <hip/hip_runtime.h>
#include <hip/hip_bf16.h>
#include <math.h>

// ---- problem constants ----
constexpr int N_    = 4;
constexpr int LQ    = 900;
constexpr int D     = 256;
constexpr int HEADS = 8;
constexpr int DH    = 32;
constexpr int NPTS  = 4;
constexpr int LEN   = 16384;   // 128*128
constexpr int H_    = 128;
constexpr int W_    = 128;
constexpr int DFF   = 1024;
constexpr int NLAYERS = 6;
constexpr int MQ    = N_ * LQ;   // 3600
constexpr int MV    = N_ * LEN;  // 65536
constexpr int MB    = (MQ + 63) / 64;   // 57
constexpr int VBLK  = (D / 128) * (MV / 128);  // 1024 value blocks
constexpr int QBLK  = 2 * MB;                  // 114 qoa blocks
constexpr int BBLK  = 4 * MB;                  // 228 b1 blocks

typedef __attribute__((ext_vector_type(8))) short bf16x8;
typedef __attribute__((ext_vector_type(4))) float f32x4;

static __device__ __forceinline__ unsigned short f2bf(float v) {
    __hip_bfloat16 h = __float2bfloat16(v);
    return *(unsigned short*)&h;
}
static __device__ __forceinline__ float bf2f(unsigned short u) {
    __hip_bfloat16 h = *(__hip_bfloat16*)&u;
    return __bfloat162float(h);
}
static __device__ __forceinline__ bf16x8 pack8(const float* a, const float* b4) {
    union { bf16x8 v; unsigned short u[8]; } o;
    o.u[0] = f2bf(a[0]); o.u[1] = f2bf(a[1]); o.u[2] = f2bf(a[2]); o.u[3] = f2bf(a[3]);
    o.u[4] = f2bf(b4[0]); o.u[5] = f2bf(b4[1]); o.u[6] = f2bf(b4[2]); o.u[7] = f2bf(b4[3]);
    return o.v;
}

// async global->LDS, 16 B per lane (LDS dest wave-uniform base + lane*16)
static __device__ __forceinline__ void gload_lds16(const void* gaddr, void* laddr) {
    __builtin_amdgcn_global_load_lds(
        (const __attribute__((address_space(1))) unsigned int*)gaddr,
        (__attribute__((address_space(3))) unsigned int*)laddr,
        16, 0, 0);
}

// =====================================================================
// fp32 -> bf16 conversion (contiguous), n8 = count/8
// =====================================================================
__global__ __launch_bounds__(256) void cvt_bf16_kernel(
    const float* __restrict__ in, unsigned short* __restrict__ out, int n8)
{
    int i = blockIdx.x * 256 + threadIdx.x;
    if (i >= n8) return;
    float4 a = ((const float4*)in)[i * 2];
    float4 b = ((const float4*)in)[i * 2 + 1];
    float af[4] = {a.x, a.y, a.z, a.w}, bff[4] = {b.x, b.y, b.z, b.w};
    *(bf16x8*)(out + (size_t)i * 8) = pack8(af, bff);
}

// =====================================================================
// 4x D x D weight transpose+cvt in one dispatch (Wv, Wout, Wb1, Wb2)
// =====================================================================
__global__ __launch_bounds__(256) void wt_cvt4_kernel(
    const float* __restrict__ W0, const float* __restrict__ W1,
    const float* __restrict__ W2, const float* __restrict__ W3,
    unsigned short* __restrict__ T0, unsigned short* __restrict__ T1,
    unsigned short* __restrict__ T2, unsigned short* __restrict__ T3)
{
    int i = blockIdx.x * 256 + threadIdx.x;
    if (i >= NLAYERS * D * D) return;
    int k = i & (D - 1);
    int n = (i >> 8) & (D - 1);
    int l = i >> 16;
    size_t si = (size_t)l * D * D + (size_t)k * D + n;
    T0[i] = f2bf(W0[si]);
    T1[i] = f2bf(W1[si]);
    T2[i] = f2bf(W2[si]);
    T3[i] = f2bf(W3[si]);
}

// =====================================================================
// Wfc (L,D,DFF) -> WfcT (L,DFF,D) and Wproj (L,DFF,D) -> WprojT (L,D,DFF)
// in one dispatch over NLAYERS*DFF*D indices.
// =====================================================================
__global__ __launch_bounds__(256) void wt_cvt2_kernel(
    const float* __restrict__ Wfc, const float* __restrict__ Wproj,
    unsigned short* __restrict__ WfcT, unsigned short* __restrict__ WprojT)
{
    int i = blockIdx.x * 256 + threadIdx.x;
    if (i >= NLAYERS * DFF * D) return;
    // WfcT layout: [l][n<DFF][k<D]  <- Wfc[l][k][n]
    {
        int k = i % D;
        int n = (i / D) % DFF;
        int l = i / (D * DFF);
        WfcT[i] = f2bf(Wfc[((size_t)l * D + k) * DFF + n]);
    }
    // WprojT layout: [l][n<D][k<DFF] <- Wproj[l][k][n]
    {
        int k = i % DFF;
        int n = (i / DFF) % D;
        int l = i / (D * DFF);
        WprojT[i] = f2bf(Wproj[((size_t)l * DFF + k) * D + n]);
    }
}

// =====================================================================
// WoaT: rows 0..63 = Wo^T (N=64), rows 64..95 = Wa^T (N=32), 96..127 = 0
// =====================================================================
__global__ __launch_bounds__(256) void woat_kernel(
    const float* __restrict__ Wo, const float* __restrict__ Wa,
    unsigned short* __restrict__ WoaT)
{
    int i = blockIdx.x * 256 + threadIdx.x;
    if (i >= NLAYERS * 128 * D) return;
    int k = i % D;
    int n = (i / D) & 127;
    int l = i / (D * 128);
    float v = 0.f;
    if (n < 64)      v = Wo[((size_t)l * D + k) * 64 + n];
    else if (n < 96) v = Wa[((size_t)l * D + k) * 32 + (n - 64)];
    WoaT[i] = f2bf(v);
}

__global__ __launch_bounds__(256) void bias_concat_kernel(
    const float* __restrict__ bo, const float* __restrict__ ba, float* __restrict__ boa)
{
    int i = blockIdx.x * 256 + threadIdx.x;
    if (i >= NLAYERS * 128) return;
    int n = i & 127;
    int l = i >> 7;
    float v = 0.f;
    if (n < 64)      v = bo[l * 64 + n];
    else if (n < 96) v = ba[l * 32 + (n - 64)];
    boa[i] = v;
}

// =====================================================================
// 3-way fused dispatch (r12-validated):
//   [0, VBLK):           value GEMM layer l+1 (128x128, XCD pairing)
//   [VBLK, VBLK+QBLK):   qoa GEMM layer l+1 (64x64, fused add)
//   [VBLK+QBLK, +BBLK):  b1 GEMM layer l (64x64, bf16 A, relu, bf16 out)
// =====================================================================
template<bool HAS_B1>
__global__ __launch_bounds__(256) void fused_vq_kernel(
    const unsigned short* __restrict__ A, const unsigned short* __restrict__ Bt,
    const float* __restrict__ bias, const unsigned char* __restrict__ mask,
    unsigned short* __restrict__ C,
    const float* __restrict__ Aq, const float* __restrict__ A2q,
    const unsigned short* __restrict__ Btq, const float* __restrict__ biasq,
    float* __restrict__ Cq,
    const unsigned short* __restrict__ Ab1, const unsigned short* __restrict__ Btb1,
    const float* __restrict__ biasb1, unsigned short* __restrict__ Cb1)
{
    __shared__ unsigned short Asm[128 * 64];
    __shared__ unsigned short Bsm[128 * 64];

    const int bid  = blockIdx.x;
    const int tid  = threadIdx.x;
    const int wave = tid >> 6;
    const int lane = tid & 63;
    const int lg   = lane >> 4;
    const int lr   = lane & 15;

    if (bid < VBLK) {
        const int y  = (bid >> 4) * 8 + (bid & 7);
        const int x  = (bid >> 3) & 1;
        const int m0 = y * 128;
        const int n0 = x * 128;
        const int wr = wave >> 1;
        const int wc = wave & 1;

        f32x4 acc[4][4];
#pragma unroll
        for (int i = 0; i < 4; ++i)
#pragma unroll
            for (int j = 0; j < 4; ++j) acc[i][j] = (f32x4){0.f, 0.f, 0.f, 0.f};

        for (int k0 = 0; k0 < D; k0 += 64) {
#pragma unroll
            for (int it = 0; it < 4; ++it) {
                int c   = tid + it * 256;
                int row = c >> 3;
                int kch = (c & 7) ^ (row & 7);
                unsigned ldsoff = (unsigned)(it * 256 + wave * 64) * 16;
                gload_lds16(A  + (size_t)(m0 + row) * D + k0 + kch * 8, (char*)Asm + ldsoff);
                gload_lds16(Bt + (size_t)(n0 + row) * D + k0 + kch * 8, (char*)Bsm + ldsoff);
            }
            __syncthreads();

            bf16x8 af[4][2], bfr[4][2];
#pragma unroll
            for (int i = 0; i < 4; ++i) {
#pragma unroll
                for (int kk = 0; kk < 2; ++kk) {
                    int arow = wr * 64 + i * 16 + lr;
                    af[i][kk]  = *(const bf16x8*)((char*)Asm + arow * 128 + 16 * ((kk * 4 + lg) ^ (arow & 7)));
                    int brow = wc * 64 + i * 16 + lr;
                    bfr[i][kk] = *(const bf16x8*)((char*)Bsm + brow * 128 + 16 * ((kk * 4 + lg) ^ (brow & 7)));
                }
            }
#pragma unroll
            for (int kk = 0; kk < 2; ++kk)
#pragma unroll
                for (int i = 0; i < 4; ++i)
#pragma unroll
                    for (int j = 0; j < 4; ++j)
                        acc[i][j] = __builtin_amdgcn_mfma_f32_16x16x32_bf16(
                            af[i][kk], bfr[j][kk], acc[i][j], 0, 0, 0);
            __syncthreads();
        }

#pragma unroll
        for (int i = 0; i < 4; ++i) {
            int mbase = m0 + wr * 64 + i * 16 + lg * 4;
#pragma unroll
            for (int j = 0; j < 4; ++j) {
                int n = n0 + wc * 64 + j * 16 + lr;
                float bn = bias[n];
#pragma unroll
                for (int r = 0; r < 4; ++r) {
                    int m = mbase + r;
                    float v = acc[i][j][r] + bn;
                    if (mask[m]) v = 0.f;
                    C[(size_t)m * D + n] = f2bf(v);
                }
            }
        }
    } else if (bid < VBLK + QBLK) {
        const int qb = bid - VBLK;
        const int n0 = (qb & 1) * 64;
        const int m0 = (qb >> 1) * 64;
        const int wr = wave >> 1;
        const int wc = wave & 1;

        f32x4 acc[2][2];
#pragma unroll
        for (int i = 0; i < 2; ++i)
#pragma unroll
            for (int j = 0; j < 2; ++j) acc[i][j] = (f32x4){0.f, 0.f, 0.f, 0.f};

        for (int k0 = 0; k0 < D; k0 += 64) {
#pragma unroll
            for (int it = 0; it < 2; ++it) {
                int c   = tid + it * 256;
                int row = c >> 3;
                int kc  = c & 7;
                int kch = kc ^ (row & 7);
                unsigned ldsoff = (unsigned)(it * 256 + wave * 64) * 16;
                gload_lds16(Btq + (size_t)(n0 + row) * D + k0 + kch * 8, (char*)Bsm + ldsoff);
                int gm = m0 + row;
                bf16x8 v = (bf16x8){0,0,0,0,0,0,0,0};
                if (gm < MQ) {
                    const float* ap = Aq  + (size_t)gm * D + k0 + kc * 8;
                    const float* qp = A2q + (size_t)gm * D + k0 + kc * 8;
                    float4 a = *(const float4*)ap;
                    float4 b = *(const float4*)(ap + 4);
                    float4 qa = *(const float4*)qp;
                    float4 qb4 = *(const float4*)(qp + 4);
                    a.x += qa.x; a.y += qa.y; a.z += qa.z; a.w += qa.w;
                    b.x += qb4.x; b.y += qb4.y; b.z += qb4.z; b.w += qb4.w;
                    float af_[4] = {a.x, a.y, a.z, a.w}, bf_[4] = {b.x, b.y, b.z, b.w};
                    v = pack8(af_, bf_);
                }
                *(bf16x8*)((char*)Asm + row * 128 + 16 * (kc ^ (row & 7))) = v;
            }
            __syncthreads();

            bf16x8 af[2][2], bfr[2][2];
#pragma unroll
            for (int i = 0; i < 2; ++i) {
#pragma unroll
                for (int kk = 0; kk < 2; ++kk) {
                    int arow = wr * 32 + i * 16 + lr;
                    af[i][kk]  = *(const bf16x8*)((char*)Asm + arow * 128 + 16 * ((kk * 4 + lg) ^ (arow & 7)));
                    int brow = wc * 32 + i * 16 + lr;
                    bfr[i][kk] = *(const bf16x8*)((char*)Bsm + brow * 128 + 16 * ((kk * 4 + lg) ^ (brow & 7)));
                }
            }
#pragma unroll
            for (int kk = 0; kk < 2; ++kk)
#pragma unroll
                for (int i = 0; i < 2; ++i)
#pragma unroll
                    for (int j = 0; j < 2; ++j)
                        acc[i][j] = __builtin_amdgcn_mfma_f32_16x16x32_bf16(
                            af[i][kk], bfr[j][kk], acc[i][j], 0, 0, 0);
            __syncthreads();
        }

#pragma unroll
        for (int i = 0; i < 2; ++i) {
            int mbase = m0 + wr * 32 + i * 16 + lg * 4;
#pragma unroll
            for (int j = 0; j < 2; ++j) {
                int n = n0 + wc * 32 + j * 16 + lr;
                if (n >= 96) continue;
                float bn = biasq[n];
#pragma unroll
                for (int r = 0; r < 4; ++r) {
                    int m = mbase + r;
                    if (m >= MQ) continue;
                    Cq[(size_t)m * 96 + n] = acc[i][j][r] + bn;
                }
            }
        }
    } else if (HAS_B1) {
        const int bb = bid - VBLK - QBLK;
        const int n0 = (bb & 3) * 64;
        const int m0 = (bb >> 2) * 64;
        const int wr = wave >> 1;
        const int wc = wave & 1;

        f32x4 acc[2][2];
#pragma unroll
        for (int i = 0; i < 2; ++i)
#pragma unroll
            for (int j = 0; j < 2; ++j) acc[i][j] = (f32x4){0.f, 0.f, 0.f, 0.f};

        for (int k0 = 0; k0 < D; k0 += 64) {
#pragma unroll
            for (int it = 0; it < 2; ++it) {
                int c   = tid + it * 256;
                int row = c >> 3;
                int kch = (c & 7) ^ (row & 7);
                unsigned ldsoff = (unsigned)(it * 256 + wave * 64) * 16;
                gload_lds16(Btb1 + (size_t)(n0 + row) * D + k0 + kch * 8, (char*)Bsm + ldsoff);
                gload_lds16(Ab1  + (size_t)(m0 + row) * D + k0 + kch * 8, (char*)Asm + ldsoff);
            }
            __syncthreads();

            bf16x8 af[2][2], bfr[2][2];
#pragma unroll
            for (int i = 0; i < 2; ++i) {
#pragma unroll
                for (int kk = 0; kk < 2; ++kk) {
                    int arow = wr * 32 + i * 16 + lr;
                    af[i][kk]  = *(const bf16x8*)((char*)Asm + arow * 128 + 16 * ((kk * 4 + lg) ^ (arow & 7)));
                    int brow = wc * 32 + i * 16 + lr;
                    bfr[i][kk] = *(const bf16x8*)((char*)Bsm + brow * 128 + 16 * ((kk * 4 + lg) ^ (brow & 7)));
                }
            }
#pragma unroll
            for (int kk = 0; kk < 2; ++kk)
#pragma unroll
                for (int i = 0; i < 2; ++i)
#pragma unroll
                    for (int j = 0; j < 2; ++j)
                        acc[i][j] = __builtin_amdgcn_mfma_f32_16x16x32_bf16(
                            af[i][kk], bfr[j][kk], acc[i][j], 0, 0, 0);
            __syncthreads();
        }

#pragma unroll
        for (int i = 0; i < 2; ++i) {
            int mbase = m0 + wr * 32 + i * 16 + lg * 4;
#pragma unroll
            for (int j = 0; j < 2; ++j) {
                int n = n0 + wc * 32 + j * 16 + lr;
#pragma unroll
                for (int r = 0; r < 4; ++r) {
                    int m = mbase + r;
                    if (m >= MQ) continue;
                    float v = fmaxf(acc[i][j][r] + biasb1[n], 0.f);
                    Cb1[(size_t)m * D + n] = f2bf(v);
                }
            }
        }
    }
}

// =====================================================================
// MFMA query GEMM: C[M,Nreal] = A[M,K] @ Bt^T + bias (+relu). (r10-validated)
// =====================================================================
template<bool ABF16, bool RELU, bool OUTBF16>
__global__ __launch_bounds__(256) void gemm_q_mfma(
    const void* __restrict__ Av,
    const unsigned short* __restrict__ Bt, const float* __restrict__ bias,
    void* __restrict__ Cv, int M, int Nreal, int K)
{
    __shared__ unsigned short Asm[64 * 64];
    __shared__ unsigned short Bsm[64 * 64];

    const int tid  = threadIdx.x;
    const int m0   = blockIdx.y * 64;
    const int n0   = blockIdx.x * 64;
    const int wave = tid >> 6;
    const int lane = tid & 63;
    const int wr   = wave >> 1;
    const int wc   = wave & 1;
    const int lg   = lane >> 4;
    const int lr   = lane & 15;

    f32x4 acc[2][2];
#pragma unroll
    for (int i = 0; i < 2; ++i)
#pragma unroll
        for (int j = 0; j < 2; ++j) acc[i][j] = (f32x4){0.f, 0.f, 0.f, 0.f};

    for (int k0 = 0; k0 < K; k0 += 64) {
#pragma unroll
        for (int it = 0; it < 2; ++it) {
            int c   = tid + it * 256;
            int row = c >> 3;
            int kch = (c & 7) ^ (row & 7);
            unsigned ldsoff = (unsigned)(it * 256 + wave * 64) * 16;
            gload_lds16(Bt + (size_t)(n0 + row) * K + k0 + kch * 8, (char*)Bsm + ldsoff);
            if (ABF16) {
                gload_lds16((const unsigned short*)Av + (size_t)(m0 + row) * K + k0 + kch * 8,
                            (char*)Asm + ldsoff);
            } else {
                int kc = c & 7;
                int gm = m0 + row;
                bf16x8 v = (bf16x8){0,0,0,0,0,0,0,0};
                if (gm < M) {
                    const float* ap = (const float*)Av + (size_t)gm * K + k0 + kc * 8;
                    float4 a = *(const float4*)ap;
                    float4 b = *(const float4*)(ap + 4);
                    float af_[4] = {a.x, a.y, a.z, a.w}, bf_[4] = {b.x, b.y, b.z, b.w};
                    v = pack8(af_, bf_);
                }
                *(bf16x8*)((char*)Asm + row * 128 + 16 * (kc ^ (row & 7))) = v;
            }
        }
        __syncthreads();

        bf16x8 af[2][2], bfr[2][2];
#pragma unroll
        for (int i = 0; i < 2; ++i) {
#pragma unroll
            for (int kk = 0; kk < 2; ++kk) {
                int arow = wr * 32 + i * 16 + lr;
                af[i][kk]  = *(const bf16x8*)((char*)Asm + arow * 128 + 16 * ((kk * 4 + lg) ^ (arow & 7)));
                int brow = wc * 32 + i * 16 + lr;
                bfr[i][kk] = *(const bf16x8*)((char*)Bsm + brow * 128 + 16 * ((kk * 4 + lg) ^ (brow & 7)));
            }
        }
#pragma unroll
        for (int kk = 0; kk < 2; ++kk)
#pragma unroll
            for (int i = 0; i < 2; ++i)
#pragma unroll
                for (int j = 0; j < 2; ++j)
                    acc[i][j] = __builtin_amdgcn_mfma_f32_16x16x32_bf16(
                        af[i][kk], bfr[j][kk], acc[i][j], 0, 0, 0);
        __syncthreads();
    }

#pragma unroll
    for (int i = 0; i < 2; ++i) {
        int mbase = m0 + wr * 32 + i * 16 + lg * 4;
#pragma unroll
        for (int j = 0; j < 2; ++j) {
            int n = n0 + wc * 32 + j * 16 + lr;
            if (n >= Nreal) continue;
            float bn = bias[n];
#pragma unroll
            for (int r = 0; r < 4; ++r) {
                int m = mbase + r;
                if (m >= M) continue;
                float v = acc[i][j][r] + bn;
                if (RELU) v = fmaxf(v, 0.f);
                if (OUTBF16) ((unsigned short*)Cv)[(size_t)m * Nreal + n] = f2bf(v);
                else         ((float*)Cv)[(size_t)m * Nreal + n] = v;
            }
        }
    }
}

// =====================================================================
// LN over D=256: out = LN(a+b)*g + be; bf16 copy outh.
// =====================================================================
__global__ __launch_bounds__(256) void ln_kernel(
    const float* __restrict__ a, const float* __restrict__ b,
    const float* __restrict__ g, const float* __restrict__ be,
    float* __restrict__ out, unsigned short* __restrict__ outh)
{
    int row  = blockIdx.x * 4 + (threadIdx.x >> 6);
    int lane = threadIdx.x & 63;
    if (row >= MQ) return;

    const float4 va = *(const float4*)(a + (size_t)row * D + lane * 4);
    const float4 vb = *(const float4*)(b + (size_t)row * D + lane * 4);
    float x[4] = { va.x + vb.x, va.y + vb.y, va.z + vb.z, va.w + vb.w };

    float s = x[0] + x[1] + x[2] + x[3];
    float s2 = x[0]*x[0] + x[1]*x[1] + x[2]*x[2] + x[3]*x[3];
#pragma unroll
    for (int o = 32; o >= 1; o >>= 1) {
        s  += __shfl_xor(s,  o);
        s2 += __shfl_xor(s2, o);
    }
    float mean = s * (1.f / D);
    float var  = s2 * (1.f / D) - mean * mean;
    float rinv = rsqrtf(var + 1e-5f);

    float4 vg = *(const float4*)(g  + lane * 4);
    float4 vbe = *(const float4*)(be + lane * 4);
    float4 vo;
    vo.x = (x[0] - mean) * rinv * vg.x + vbe.x;
    vo.y = (x[1] - mean) * rinv * vg.y + vbe.y;
    vo.z = (x[2] - mean) * rinv * vg.z + vbe.z;
    vo.w = (x[3] - mean) * rinv * vg.w + vbe.w;
    *(float4*)(out + (size_t)row * D + lane * 4) = vo;

    ushort4 ho;
    ho.x = f2bf(vo.x); ho.y = f2bf(vo.y); ho.z = f2bf(vo.z); ho.w = f2bf(vo.w);
    *(ushort4*)(outh + (size_t)row * D + lane * 4) = ho;
}

// =====================================================================
// sample kernel, 64 threads/block (1 wave), one query per block.
// Each thread owns 4 elements (u64 = 4 bf16): h = tid>>3, e0 = (tid&7)*4.
// Halves gather transaction count vs r16's u32-pair. Optional inline
// bbox-refinement of the previous layer (the single wave). attn bf16 (u64).
// =====================================================================
template<bool IREF>
__global__ __launch_bounds__(64) void sample_kernel(
    const unsigned short* __restrict__ value, const float* __restrict__ qoa,
    const float* __restrict__ ref_in,
    const unsigned short* __restrict__ t2,
    const float* __restrict__ Wb3, const float* __restrict__ bb3,
    float* __restrict__ ref_out,
    const float* __restrict__ svr,
    unsigned short* __restrict__ attn)
{
    __shared__ float refs[4];

    int nq = blockIdx.x;
    int h  = threadIdx.x >> 3;          // 0..7
    int e0 = (threadIdx.x & 7) * 4;     // 0,4,..,28
    int n  = nq / LQ;

    if (IREF) {
        int lane = threadIdx.x;
        float a0 = 0.f, a1 = 0.f, a2 = 0.f, a3 = 0.f;
        const unsigned short* tp = t2 + (size_t)nq * D;
#pragma unroll
        for (int kk = 0; kk < D / 64; ++kk) {
            int k = lane + kk * 64;
            float tv = bf2f(tp[k]);
            const float4 wrow = *(const float4*)(Wb3 + (size_t)k * 4);
            a0 = fmaf(tv, wrow.x, a0);
            a1 = fmaf(tv, wrow.y, a1);
            a2 = fmaf(tv, wrow.z, a2);
            a3 = fmaf(tv, wrow.w, a3);
        }
#pragma unroll
        for (int o = 32; o >= 1; o >>= 1) {
            a0 += __shfl_xor(a0, o);
            a1 += __shfl_xor(a1, o);
            a2 += __shfl_xor(a2, o);
            a3 += __shfl_xor(a3, o);
        }
        if (lane == 0) {
            float t3[4] = { a0 + bb3[0], a1 + bb3[1], a2 + bb3[2], a3 + bb3[3] };
#pragma unroll
            for (int c = 0; c < 4; ++c) {
                float rp = ref_in[(size_t)nq * 4 + c];
                float xc = fminf(fmaxf(rp, 0.f), 1.f);
                float invsig = logf(fmaxf(xc, 1e-5f) / fmaxf(1.f - xc, 1e-5f));
                float rv = 1.f / (1.f + expf(-(t3[c] + invsig)));
                refs[c] = rv;
                ref_out[(size_t)nq * 4 + c] = rv;
            }
        }
        __syncthreads();
    }

    float vr0 = svr[n * 2 + 0], vr1 = svr[n * 2 + 1];
    float rr0, rr1, rr2, rr3;
    if (IREF) {
        rr0 = refs[0]; rr1 = refs[1]; rr2 = refs[2]; rr3 = refs[3];
    } else {
        rr0 = ref_in[nq * 4 + 0]; rr1 = ref_in[nq * 4 + 1];
        rr2 = ref_in[nq * 4 + 2]; rr3 = ref_in[nq * 4 + 3];
    }
    float r0 = rr0 * vr0;
    float r1 = rr1 * vr1;
    float r2 = rr2 * vr0;
    float r3 = rr3 * vr1;

    const float* qrow = qoa + (size_t)nq * 96;

    float lgt[4];
    float mx = -1e30f;
#pragma unroll
    for (int p = 0; p < 4; ++p) {
        lgt[p] = qrow[64 + h * 4 + p];
        mx = fmaxf(mx, lgt[p]);
    }
    float ssum = 0.f;
#pragma unroll
    for (int p = 0; p < 4; ++p) { lgt[p] = expf(lgt[p] - mx); ssum += lgt[p]; }
    float sinv = 1.f / ssum;

    const unsigned short* vbase = value + (size_t)n * LEN * D + h * DH + e0;
    float acc0 = 0.f, acc1 = 0.f, acc2 = 0.f, acc3 = 0.f;

#pragma unroll
    for (int p = 0; p < NPTS; ++p) {
        float ox = qrow[h * 8 + p * 2 + 0];
        float oy = qrow[h * 8 + p * 2 + 1];
        float lx = r0 + ox * (1.f / NPTS) * r2 * 0.5f;
        float ly = r1 + oy * (1.f / NPTS) * r3 * 0.5f;
        float w  = lgt[p] * sinv;

        float x = lx * W_ - 0.5f;
        float y = ly * H_ - 0.5f;
        x = fminf(fmaxf(x, -1e4f), 1e4f);
        y = fminf(fmaxf(y, -1e4f), 1e4f);
        float x0f = floorf(x), y0f = floorf(y);
        float wx = x - x0f, wy = y - y0f;
        int x0 = (int)x0f, y0 = (int)y0f;

        float cw[4] = { (1.f - wx) * (1.f - wy), wx * (1.f - wy),
                        (1.f - wx) * wy,         wx * wy };
        int xs[4] = { x0, x0 + 1, x0,     x0 + 1 };
        int ys[4] = { y0, y0,     y0 + 1, y0 + 1 };

#pragma unroll
        for (int c = 0; c < 4; ++c) {
            int xi = xs[c], yi = ys[c];
            bool ok = (xi >= 0) & (xi < W_) & (yi >= 0) & (yi < H_);
            if (!ok) continue;
            unsigned long long pv = *(const unsigned long long*)(vbase + (size_t)(yi * W_ + xi) * D);
            float coeff = w * cw[c];
            acc0 = fmaf(coeff, bf2f((unsigned short)(pv & 0xffff)),         acc0);
            acc1 = fmaf(coeff, bf2f((unsigned short)((pv >> 16) & 0xffff)), acc1);
            acc2 = fmaf(coeff, bf2f((unsigned short)((pv >> 32) & 0xffff)), acc2);
            acc3 = fmaf(coeff, bf2f((unsigned short)(pv >> 48)),            acc3);
        }
    }
    unsigned long long outp =
          (unsigned long long)f2bf(acc0)
        | ((unsigned long long)f2bf(acc1) << 16)
        | ((unsigned long long)f2bf(acc2) << 32)
        | ((unsigned long long)f2bf(acc3) << 48);
    *(unsigned long long*)(attn + (size_t)nq * D + h * DH + e0) = outp;
}

// =====================================================================
// bbox final (LAST layer only)
// =====================================================================
__global__ __launch_bounds__(256) void bbox_kernel(
    const unsigned short* __restrict__ t2, const float* __restrict__ Wb3,
    const float* __restrict__ bb3, const float* __restrict__ ref_prev,
    float* __restrict__ ref_out)
{
    int row  = blockIdx.x * 4 + (threadIdx.x >> 6);
    int lane = threadIdx.x & 63;
    if (row >= MQ) return;

    float acc0 = 0.f, acc1 = 0.f, acc2 = 0.f, acc3 = 0.f;
    const unsigned short* tp = t2 + (size_t)row * D;
#pragma unroll
    for (int kk = 0; kk < D / 64; ++kk) {
        int k = lane + kk * 64;
        float tv = bf2f(tp[k]);
        const float4 wrow = *(const float4*)(Wb3 + (size_t)k * 4);
        acc0 = fmaf(tv, wrow.x, acc0);
        acc1 = fmaf(tv, wrow.y, acc1);
        acc2 = fmaf(tv, wrow.z, acc2);
        acc3 = fmaf(tv, wrow.w, acc3);
    }
#pragma unroll
    for (int o = 32; o >= 1; o >>= 1) {
        acc0 += __shfl_xor(acc0, o);
        acc1 += __shfl_xor(acc1, o);
        acc2 += __shfl_xor(acc2, o);
        acc3 += __shfl_xor(acc3, o);
    }
    if (lane == 0) {
        float t3[4] = { acc0 + bb3[0], acc1 + bb3[1], acc2 + bb3[2], acc3 + bb3[3] };
#pragma unroll
        for (int c = 0; c < 4; ++c) {
            float rp = ref_prev[(size_t)row * 4 + c];
            float xc = fminf(fmaxf(rp, 0.f), 1.f);
            float invsig = logf(fmaxf(xc, 1e-5f) / fmaxf(1.f - xc, 1e-5f));
            float sarg = t3[c] + invsig;
            ref_out[(size_t)row * 4 + c] = 1.f / (1.f + expf(-sarg));
        }
    }
}

// =====================================================================
// launcher
// =====================================================================
extern "C" void kernel_launch(void* const* d_in, const int* in_sizes, int n_in,
                              void* d_out, int out_size, void* d_ws, size_t ws_size,
                              hipStream_t stream)
{
    const float* tgt    = (const float*)d_in[0];
    const float* refpts = (const float*)d_in[1];
    const float* src    = (const float*)d_in[2];
    const float* svr    = (const float*)d_in[3];
    const float* qpos   = (const float*)d_in[4];
    const float* Wo     = (const float*)d_in[5];
    const float* bo     = (const float*)d_in[6];
    const float* Wa     = (const float*)d_in[7];
    const float* ba     = (const float*)d_in[8];
    const float* Wv     = (const float*)d_in[9];
    const float* bv     = (const float*)d_in[10];
    const float* Wout   = (const float*)d_in[11];
    const float* bout   = (const float*)d_in[12];
    const float* g1     = (const float*)d_in[13];
    const float* b1     = (const float*)d_in[14];
    const float* Wfc    = (const float*)d_in[15];
    const float* bfc    = (const float*)d_in[16];
    const float* Wproj  = (const float*)d_in[17];
    const float* bproj  = (const float*)d_in[18];
    const float* g2     = (const float*)d_in[19];
    const float* b2     = (const float*)d_in[20];
    const float* Wb1    = (const float*)d_in[21];
    const float* bb1    = (const float*)d_in[22];
    const float* Wb2    = (const float*)d_in[23];
    const float* bb2    = (const float*)d_in[24];
    const float* Wb3    = (const float*)d_in[25];
    const float* bb3    = (const float*)d_in[26];
    const unsigned char* mask = (const unsigned char*)d_in[29];

    float* outp  = (float*)d_out;
    float* inter     = outp;                             // (6, N, LQ, D)
    float* inter_ref = outp + (size_t)NLAYERS * MQ * D;  // (6, N, LQ, 4)

    // workspace carve-up
    char* wsb = (char*)d_ws;
    unsigned short* value    = (unsigned short*)wsb;  wsb += (size_t)MV * D * 2;  // 32 MiB
    unsigned short* src_bf16 = (unsigned short*)wsb;  wsb += (size_t)MV * D * 2;  // 32 MiB
    unsigned short* WvT      = (unsigned short*)wsb;  wsb += (size_t)NLAYERS * D * D * 2;
    unsigned short* WoaT     = (unsigned short*)wsb;  wsb += (size_t)NLAYERS * 128 * D * 2;
    unsigned short* WoutT    = (unsigned short*)wsb;  wsb += (size_t)NLAYERS * D * D * 2;
    unsigned short* WfcT     = (unsigned short*)wsb;  wsb += (size_t)NLAYERS * DFF * D * 2;
    unsigned short* WprojT   = (unsigned short*)wsb;  wsb += (size_t)NLAYERS * D * DFF * 2;
    unsigned short* Wb1T     = (unsigned short*)wsb;  wsb += (size_t)NLAYERS * D * D * 2;
    unsigned short* Wb2T     = (unsigned short*)wsb;  wsb += (size_t)NLAYERS * D * D * 2;
    unsigned short* hmlp     = (unsigned short*)wsb;  wsb += (size_t)MQ * DFF * 2;
    unsigned short* t1b      = (unsigned short*)wsb;  wsb += (size_t)MQ * D * 2;
    unsigned short* t2b      = (unsigned short*)wsb;  wsb += (size_t)MQ * D * 2;
    unsigned short* x1h      = (unsigned short*)wsb;  wsb += (size_t)MQ * D * 2;
    unsigned short* x2h      = (unsigned short*)wsb;  wsb += (size_t)MQ * D * 2;
    unsigned short* attnb    = (unsigned short*)wsb;  wsb += (size_t)MQ * D * 2;
    float* boa   = (float*)wsb;        wsb += (size_t)NLAYERS * 128 * 4;
    float* ws    = (float*)wsb;
    float* qoab  = ws;                 size_t o = (size_t)MQ * 96;
    float* tmpb  = ws + o;             o += (size_t)MQ * D;
    float* x1b   = ws + o;             o += (size_t)MQ * D;

    // ---- one-time conversions (5 dispatches) ----
    cvt_bf16_kernel<<<(MV * D / 8 + 255) / 256, 256, 0, stream>>>(src, src_bf16, MV * D / 8);
    {
        int t = NLAYERS * D * D;
        wt_cvt4_kernel<<<(t + 255) / 256, 256, 0, stream>>>(
            Wv, Wout, Wb1, Wb2, WvT, WoutT, Wb1T, Wb2T);
        t = NLAYERS * DFF * D;
        wt_cvt2_kernel<<<(t + 255) / 256, 256, 0, stream>>>(Wfc, Wproj, WfcT, WprojT);
        t = NLAYERS * 128 * D;
        woat_kernel<<<(t + 255) / 256, 256, 0, stream>>>(Wo, Wa, WoaT);
        bias_concat_kernel<<<(NLAYERS * 128 + 255) / 256, 256, 0, stream>>>(bo, ba, boa);
    }

    // ---- layer-0 prologue: value(0) + qoa(0) ----
    fused_vq_kernel<false><<<VBLK + QBLK, 256, 0, stream>>>(
        src_bf16, WvT, bv, mask, value,
        tgt, qpos, WoaT, boa, qoab,
        nullptr, nullptr, nullptr, nullptr);

    for (int l = 0; l < NLAYERS; ++l) {
        const float* out_prev = (l == 0) ? tgt : inter + (size_t)(l - 1) * MQ * D;
        float* inter_l = inter + (size_t)l * MQ * D;

        // 1) sample (+ inline ref(l-1) refinement for l>=1) -> attn bf16
        if (l == 0) {
            sample_kernel<false><<<MQ, 64, 0, stream>>>(
                value, qoab, refpts, nullptr, nullptr, nullptr, nullptr, svr, attnb);
        } else {
            const float* ref_pp = (l == 1) ? refpts : inter_ref + (size_t)(l - 2) * MQ * 4;
            sample_kernel<true><<<MQ, 64, 0, stream>>>(
                value, qoab, ref_pp, t2b,
                Wb3 + (size_t)(l - 1) * D * 4, bb3 + (size_t)(l - 1) * 4,
                inter_ref + (size_t)(l - 1) * MQ * 4, svr, attnb);
        }

        // 2) attn(bf16) @ Wout + bout  (228 blocks, full async staging)
        gemm_q_mfma<true,false,false><<<dim3(4, MB), 256, 0, stream>>>(
            attnb, WoutT + (size_t)l * D * D, bout + (size_t)l * D, tmpb, MQ, D, D);

        // 3) x1 = LN(out_prev + tmp) -> fp32 + bf16
        ln_kernel<<<MQ / 4, 256, 0, stream>>>(
            out_prev, tmpb, g1 + (size_t)l * D, b1 + (size_t)l * D, x1b, x1h);

        // 4) h = relu(x1h @ Wfc + bfc) -> bf16  (64x64 tile, 912 blocks)
        gemm_q_mfma<true,true,true><<<dim3(DFF / 64, MB), 256, 0, stream>>>(
            x1h, WfcT + (size_t)l * DFF * D, bfc + (size_t)l * DFF, hmlp, MQ, DFF, D);

        // 5) proj: h @ Wproj + bproj  (228 blocks)
        gemm_q_mfma<true,false,false><<<dim3(4, MB), 256, 0, stream>>>(
            hmlp, WprojT + (size_t)l * D * DFF, bproj + (size_t)l * D, tmpb, MQ, D, DFF);

        // 6) x2 = LN(x1 + tmp) -> inter[l] fp32 + bf16
        ln_kernel<<<MQ / 4, 256, 0, stream>>>(
            x1b, tmpb, g2 + (size_t)l * D, b2 + (size_t)l * D, inter_l, x2h);

        // 7) b1(l) overlapped with value(l+1)+qoa(l+1)  [l<5]; plain b1 on last layer
        if (l < NLAYERS - 1) {
            fused_vq_kernel<true><<<VBLK + QBLK + BBLK, 256, 0, stream>>>(
                src_bf16, WvT + (size_t)(l + 1) * D * D, bv + (size_t)(l + 1) * D, mask, value,
                inter_l, qpos, WoaT + (size_t)(l + 1) * 128 * D, boa + (size_t)(l + 1) * 128, qoab,
                x2h, Wb1T + (size_t)l * D * D, bb1 + (size_t)l * D, t1b);
        } else {
            gemm_q_mfma<true,true,true><<<dim3(4, MB), 256, 0, stream>>>(
                x2h, Wb1T + (size_t)l * D * D, bb1 + (size_t)l * D, t1b, MQ, D, D);
        }

        // 8) t2 = relu(t1 @ Wb2 + bb2) -> bf16
        gemm_q_mfma<true,true,true><<<dim3(4, MB), 256, 0, stream>>>(
            t1b, Wb2T + (size_t)l * D * D, bb2 + (size_t)l * D, t2b, MQ, D, D);

        // 9) bbox only for the LAST layer
        if (l == NLAYERS - 1) {
            bbox_kernel<<<MQ / 4, 256, 0, stream>>>(
                t2b, Wb3 + (size_t)l * D * 4, bb3 + (size_t)l * 4,
                inter_ref + (size_t)(l - 1) * MQ * 4, inter_ref + (size_t)l * MQ * 4);
        }
    }
}

// Round 18
// 527.919 us; speedup vs baseline: 1.1524x; 1.0090x over previous
//
#include <hip/hip_runtime.h>
#include <hip/hip_bf16.h>
#include <math.h>

// ---- problem constants ----
constexpr int N_    = 4;
constexpr int LQ    = 900;
constexpr int D     = 256;
constexpr int HEADS = 8;
constexpr int DH    = 32;
constexpr int NPTS  = 4;
constexpr int LEN   = 16384;   // 128*128
constexpr int H_    = 128;
constexpr int W_    = 128;
constexpr int DFF   = 1024;
constexpr int NLAYERS = 6;
constexpr int MQ    = N_ * LQ;   // 3600
constexpr int MV    = N_ * LEN;  // 65536
constexpr int MB    = (MQ + 63) / 64;   // 57
constexpr int VBLK  = (D / 128) * (MV / 128);  // 1024 value blocks
constexpr int QBLK  = 2 * MB;                  // 114 qoa blocks
constexpr int BBLK  = 4 * MB;                  // 228 b1 blocks

typedef __attribute__((ext_vector_type(8))) short bf16x8;
typedef __attribute__((ext_vector_type(4))) float f32x4;

static __device__ __forceinline__ unsigned short f2bf(float v) {
    __hip_bfloat16 h = __float2bfloat16(v);
    return *(unsigned short*)&h;
}
static __device__ __forceinline__ float bf2f(unsigned short u) {
    __hip_bfloat16 h = *(__hip_bfloat16*)&u;
    return __bfloat162float(h);
}
static __device__ __forceinline__ bf16x8 pack8(const float* a, const float* b4) {
    union { bf16x8 v; unsigned short u[8]; } o;
    o.u[0] = f2bf(a[0]); o.u[1] = f2bf(a[1]); o.u[2] = f2bf(a[2]); o.u[3] = f2bf(a[3]);
    o.u[4] = f2bf(b4[0]); o.u[5] = f2bf(b4[1]); o.u[6] = f2bf(b4[2]); o.u[7] = f2bf(b4[3]);
    return o.v;
}

// async global->LDS, 16 B per lane (LDS dest wave-uniform base + lane*16)
static __device__ __forceinline__ void gload_lds16(const void* gaddr, void* laddr) {
    __builtin_amdgcn_global_load_lds(
        (const __attribute__((address_space(1))) unsigned int*)gaddr,
        (__attribute__((address_space(3))) unsigned int*)laddr,
        16, 0, 0);
}

// =====================================================================
// fp32 -> bf16 conversion (contiguous), n8 = count/8
// =====================================================================
__global__ __launch_bounds__(256) void cvt_bf16_kernel(
    const float* __restrict__ in, unsigned short* __restrict__ out, int n8)
{
    int i = blockIdx.x * 256 + threadIdx.x;
    if (i >= n8) return;
    float4 a = ((const float4*)in)[i * 2];
    float4 b = ((const float4*)in)[i * 2 + 1];
    float af[4] = {a.x, a.y, a.z, a.w}, bff[4] = {b.x, b.y, b.z, b.w};
    *(bf16x8*)(out + (size_t)i * 8) = pack8(af, bff);
}

// =====================================================================
// 4x D x D weight transpose+cvt in one dispatch (Wv, Wout, Wb1, Wb2)
// =====================================================================
__global__ __launch_bounds__(256) void wt_cvt4_kernel(
    const float* __restrict__ W0, const float* __restrict__ W1,
    const float* __restrict__ W2, const float* __restrict__ W3,
    unsigned short* __restrict__ T0, unsigned short* __restrict__ T1,
    unsigned short* __restrict__ T2, unsigned short* __restrict__ T3)
{
    int i = blockIdx.x * 256 + threadIdx.x;
    if (i >= NLAYERS * D * D) return;
    int k = i & (D - 1);
    int n = (i >> 8) & (D - 1);
    int l = i >> 16;
    size_t si = (size_t)l * D * D + (size_t)k * D + n;
    T0[i] = f2bf(W0[si]);
    T1[i] = f2bf(W1[si]);
    T2[i] = f2bf(W2[si]);
    T3[i] = f2bf(W3[si]);
}

// =====================================================================
// Wfc (L,D,DFF) -> WfcT (L,DFF,D) and Wproj (L,DFF,D) -> WprojT (L,D,DFF)
// in one dispatch over NLAYERS*DFF*D indices.
// =====================================================================
__global__ __launch_bounds__(256) void wt_cvt2_kernel(
    const float* __restrict__ Wfc, const float* __restrict__ Wproj,
    unsigned short* __restrict__ WfcT, unsigned short* __restrict__ WprojT)
{
    int i = blockIdx.x * 256 + threadIdx.x;
    if (i >= NLAYERS * DFF * D) return;
    // WfcT layout: [l][n<DFF][k<D]  <- Wfc[l][k][n]
    {
        int k = i % D;
        int n = (i / D) % DFF;
        int l = i / (D * DFF);
        WfcT[i] = f2bf(Wfc[((size_t)l * D + k) * DFF + n]);
    }
    // WprojT layout: [l][n<D][k<DFF] <- Wproj[l][k][n]
    {
        int k = i % DFF;
        int n = (i / DFF) % D;
        int l = i / (D * DFF);
        WprojT[i] = f2bf(Wproj[((size_t)l * DFF + k) * D + n]);
    }
}

// =====================================================================
// WoaT: rows 0..63 = Wo^T (N=64), rows 64..95 = Wa^T (N=32), 96..127 = 0
// =====================================================================
__global__ __launch_bounds__(256) void woat_kernel(
    const float* __restrict__ Wo, const float* __restrict__ Wa,
    unsigned short* __restrict__ WoaT)
{
    int i = blockIdx.x * 256 + threadIdx.x;
    if (i >= NLAYERS * 128 * D) return;
    int k = i % D;
    int n = (i / D) & 127;
    int l = i / (D * 128);
    float v = 0.f;
    if (n < 64)      v = Wo[((size_t)l * D + k) * 64 + n];
    else if (n < 96) v = Wa[((size_t)l * D + k) * 32 + (n - 64)];
    WoaT[i] = f2bf(v);
}

__global__ __launch_bounds__(256) void bias_concat_kernel(
    const float* __restrict__ bo, const float* __restrict__ ba, float* __restrict__ boa)
{
    int i = blockIdx.x * 256 + threadIdx.x;
    if (i >= NLAYERS * 128) return;
    int n = i & 127;
    int l = i >> 7;
    float v = 0.f;
    if (n < 64)      v = bo[l * 64 + n];
    else if (n < 96) v = ba[l * 32 + (n - 64)];
    boa[i] = v;
}

// =====================================================================
// 3-way fused dispatch (r12-validated):
//   [0, VBLK):           value GEMM layer l+1 (128x128, XCD pairing)
//   [VBLK, VBLK+QBLK):   qoa GEMM layer l+1 (64x64, fused add)
//   [VBLK+QBLK, +BBLK):  b1 GEMM layer l (64x64, bf16 A, relu, bf16 out)
// =====================================================================
template<bool HAS_B1>
__global__ __launch_bounds__(256) void fused_vq_kernel(
    const unsigned short* __restrict__ A, const unsigned short* __restrict__ Bt,
    const float* __restrict__ bias, const unsigned char* __restrict__ mask,
    unsigned short* __restrict__ C,
    const float* __restrict__ Aq, const float* __restrict__ A2q,
    const unsigned short* __restrict__ Btq, const float* __restrict__ biasq,
    float* __restrict__ Cq,
    const unsigned short* __restrict__ Ab1, const unsigned short* __restrict__ Btb1,
    const float* __restrict__ biasb1, unsigned short* __restrict__ Cb1)
{
    __shared__ unsigned short Asm[128 * 64];
    __shared__ unsigned short Bsm[128 * 64];

    const int bid  = blockIdx.x;
    const int tid  = threadIdx.x;
    const int wave = tid >> 6;
    const int lane = tid & 63;
    const int lg   = lane >> 4;
    const int lr   = lane & 15;

    if (bid < VBLK) {
        const int y  = (bid >> 4) * 8 + (bid & 7);
        const int x  = (bid >> 3) & 1;
        const int m0 = y * 128;
        const int n0 = x * 128;
        const int wr = wave >> 1;
        const int wc = wave & 1;

        f32x4 acc[4][4];
#pragma unroll
        for (int i = 0; i < 4; ++i)
#pragma unroll
            for (int j = 0; j < 4; ++j) acc[i][j] = (f32x4){0.f, 0.f, 0.f, 0.f};

        for (int k0 = 0; k0 < D; k0 += 64) {
#pragma unroll
            for (int it = 0; it < 4; ++it) {
                int c   = tid + it * 256;
                int row = c >> 3;
                int kch = (c & 7) ^ (row & 7);
                unsigned ldsoff = (unsigned)(it * 256 + wave * 64) * 16;
                gload_lds16(A  + (size_t)(m0 + row) * D + k0 + kch * 8, (char*)Asm + ldsoff);
                gload_lds16(Bt + (size_t)(n0 + row) * D + k0 + kch * 8, (char*)Bsm + ldsoff);
            }
            __syncthreads();

            bf16x8 af[4][2], bfr[4][2];
#pragma unroll
            for (int i = 0; i < 4; ++i) {
#pragma unroll
                for (int kk = 0; kk < 2; ++kk) {
                    int arow = wr * 64 + i * 16 + lr;
                    af[i][kk]  = *(const bf16x8*)((char*)Asm + arow * 128 + 16 * ((kk * 4 + lg) ^ (arow & 7)));
                    int brow = wc * 64 + i * 16 + lr;
                    bfr[i][kk] = *(const bf16x8*)((char*)Bsm + brow * 128 + 16 * ((kk * 4 + lg) ^ (brow & 7)));
                }
            }
#pragma unroll
            for (int kk = 0; kk < 2; ++kk)
#pragma unroll
                for (int i = 0; i < 4; ++i)
#pragma unroll
                    for (int j = 0; j < 4; ++j)
                        acc[i][j] = __builtin_amdgcn_mfma_f32_16x16x32_bf16(
                            af[i][kk], bfr[j][kk], acc[i][j], 0, 0, 0);
            __syncthreads();
        }

#pragma unroll
        for (int i = 0; i < 4; ++i) {
            int mbase = m0 + wr * 64 + i * 16 + lg * 4;
#pragma unroll
            for (int j = 0; j < 4; ++j) {
                int n = n0 + wc * 64 + j * 16 + lr;
                float bn = bias[n];
#pragma unroll
                for (int r = 0; r < 4; ++r) {
                    int m = mbase + r;
                    float v = acc[i][j][r] + bn;
                    if (mask[m]) v = 0.f;
                    C[(size_t)m * D + n] = f2bf(v);
                }
            }
        }
    } else if (bid < VBLK + QBLK) {
        const int qb = bid - VBLK;
        const int n0 = (qb & 1) * 64;
        const int m0 = (qb >> 1) * 64;
        const int wr = wave >> 1;
        const int wc = wave & 1;

        f32x4 acc[2][2];
#pragma unroll
        for (int i = 0; i < 2; ++i)
#pragma unroll
            for (int j = 0; j < 2; ++j) acc[i][j] = (f32x4){0.f, 0.f, 0.f, 0.f};

        for (int k0 = 0; k0 < D; k0 += 64) {
#pragma unroll
            for (int it = 0; it < 2; ++it) {
                int c   = tid + it * 256;
                int row = c >> 3;
                int kc  = c & 7;
                int kch = kc ^ (row & 7);
                unsigned ldsoff = (unsigned)(it * 256 + wave * 64) * 16;
                gload_lds16(Btq + (size_t)(n0 + row) * D + k0 + kch * 8, (char*)Bsm + ldsoff);
                int gm = m0 + row;
                bf16x8 v = (bf16x8){0,0,0,0,0,0,0,0};
                if (gm < MQ) {
                    const float* ap = Aq  + (size_t)gm * D + k0 + kc * 8;
                    const float* qp = A2q + (size_t)gm * D + k0 + kc * 8;
                    float4 a = *(const float4*)ap;
                    float4 b = *(const float4*)(ap + 4);
                    float4 qa = *(const float4*)qp;
                    float4 qb4 = *(const float4*)(qp + 4);
                    a.x += qa.x; a.y += qa.y; a.z += qa.z; a.w += qa.w;
                    b.x += qb4.x; b.y += qb4.y; b.z += qb4.z; b.w += qb4.w;
                    float af_[4] = {a.x, a.y, a.z, a.w}, bf_[4] = {b.x, b.y, b.z, b.w};
                    v = pack8(af_, bf_);
                }
                *(bf16x8*)((char*)Asm + row * 128 + 16 * (kc ^ (row & 7))) = v;
            }
            __syncthreads();

            bf16x8 af[2][2], bfr[2][2];
#pragma unroll
            for (int i = 0; i < 2; ++i) {
#pragma unroll
                for (int kk = 0; kk < 2; ++kk) {
                    int arow = wr * 32 + i * 16 + lr;
                    af[i][kk]  = *(const bf16x8*)((char*)Asm + arow * 128 + 16 * ((kk * 4 + lg) ^ (arow & 7)));
                    int brow = wc * 32 + i * 16 + lr;
                    bfr[i][kk] = *(const bf16x8*)((char*)Bsm + brow * 128 + 16 * ((kk * 4 + lg) ^ (brow & 7)));
                }
            }
#pragma unroll
            for (int kk = 0; kk < 2; ++kk)
#pragma unroll
                for (int i = 0; i < 2; ++i)
#pragma unroll
                    for (int j = 0; j < 2; ++j)
                        acc[i][j] = __builtin_amdgcn_mfma_f32_16x16x32_bf16(
                            af[i][kk], bfr[j][kk], acc[i][j], 0, 0, 0);
            __syncthreads();
        }

#pragma unroll
        for (int i = 0; i < 2; ++i) {
            int mbase = m0 + wr * 32 + i * 16 + lg * 4;
#pragma unroll
            for (int j = 0; j < 2; ++j) {
                int n = n0 + wc * 32 + j * 16 + lr;
                if (n >= 96) continue;
                float bn = biasq[n];
#pragma unroll
                for (int r = 0; r < 4; ++r) {
                    int m = mbase + r;
                    if (m >= MQ) continue;
                    Cq[(size_t)m * 96 + n] = acc[i][j][r] + bn;
                }
            }
        }
    } else if (HAS_B1) {
        const int bb = bid - VBLK - QBLK;
        const int n0 = (bb & 3) * 64;
        const int m0 = (bb >> 2) * 64;
        const int wr = wave >> 1;
        const int wc = wave & 1;

        f32x4 acc[2][2];
#pragma unroll
        for (int i = 0; i < 2; ++i)
#pragma unroll
            for (int j = 0; j < 2; ++j) acc[i][j] = (f32x4){0.f, 0.f, 0.f, 0.f};

        for (int k0 = 0; k0 < D; k0 += 64) {
#pragma unroll
            for (int it = 0; it < 2; ++it) {
                int c   = tid + it * 256;
                int row = c >> 3;
                int kch = (c & 7) ^ (row & 7);
                unsigned ldsoff = (unsigned)(it * 256 + wave * 64) * 16;
                gload_lds16(Btb1 + (size_t)(n0 + row) * D + k0 + kch * 8, (char*)Bsm + ldsoff);
                gload_lds16(Ab1  + (size_t)(m0 + row) * D + k0 + kch * 8, (char*)Asm + ldsoff);
            }
            __syncthreads();

            bf16x8 af[2][2], bfr[2][2];
#pragma unroll
            for (int i = 0; i < 2; ++i) {
#pragma unroll
                for (int kk = 0; kk < 2; ++kk) {
                    int arow = wr * 32 + i * 16 + lr;
                    af[i][kk]  = *(const bf16x8*)((char*)Asm + arow * 128 + 16 * ((kk * 4 + lg) ^ (arow & 7)));
                    int brow = wc * 32 + i * 16 + lr;
                    bfr[i][kk] = *(const bf16x8*)((char*)Bsm + brow * 128 + 16 * ((kk * 4 + lg) ^ (brow & 7)));
                }
            }
#pragma unroll
            for (int kk = 0; kk < 2; ++kk)
#pragma unroll
                for (int i = 0; i < 2; ++i)
#pragma unroll
                    for (int j = 0; j < 2; ++j)
                        acc[i][j] = __builtin_amdgcn_mfma_f32_16x16x32_bf16(
                            af[i][kk], bfr[j][kk], acc[i][j], 0, 0, 0);
            __syncthreads();
        }

#pragma unroll
        for (int i = 0; i < 2; ++i) {
            int mbase = m0 + wr * 32 + i * 16 + lg * 4;
#pragma unroll
            for (int j = 0; j < 2; ++j) {
                int n = n0 + wc * 32 + j * 16 + lr;
#pragma unroll
                for (int r = 0; r < 4; ++r) {
                    int m = mbase + r;
                    if (m >= MQ) continue;
                    float v = fmaxf(acc[i][j][r] + biasb1[n], 0.f);
                    Cb1[(size_t)m * D + n] = f2bf(v);
                }
            }
        }
    }
}

// =====================================================================
// MFMA query GEMM: C[M,Nreal] = A[M,K] @ Bt^T + bias (+relu). (r10-validated)
// =====================================================================
template<bool ABF16, bool RELU, bool OUTBF16>
__global__ __launch_bounds__(256) void gemm_q_mfma(
    const void* __restrict__ Av,
    const unsigned short* __restrict__ Bt, const float* __restrict__ bias,
    void* __restrict__ Cv, int M, int Nreal, int K)
{
    __shared__ unsigned short Asm[64 * 64];
    __shared__ unsigned short Bsm[64 * 64];

    const int tid  = threadIdx.x;
    const int m0   = blockIdx.y * 64;
    const int n0   = blockIdx.x * 64;
    const int wave = tid >> 6;
    const int lane = tid & 63;
    const int wr   = wave >> 1;
    const int wc   = wave & 1;
    const int lg   = lane >> 4;
    const int lr   = lane & 15;

    f32x4 acc[2][2];
#pragma unroll
    for (int i = 0; i < 2; ++i)
#pragma unroll
        for (int j = 0; j < 2; ++j) acc[i][j] = (f32x4){0.f, 0.f, 0.f, 0.f};

    for (int k0 = 0; k0 < K; k0 += 64) {
#pragma unroll
        for (int it = 0; it < 2; ++it) {
            int c   = tid + it * 256;
            int row = c >> 3;
            int kch = (c & 7) ^ (row & 7);
            unsigned ldsoff = (unsigned)(it * 256 + wave * 64) * 16;
            gload_lds16(Bt + (size_t)(n0 + row) * K + k0 + kch * 8, (char*)Bsm + ldsoff);
            if (ABF16) {
                gload_lds16((const unsigned short*)Av + (size_t)(m0 + row) * K + k0 + kch * 8,
                            (char*)Asm + ldsoff);
            } else {
                int kc = c & 7;
                int gm = m0 + row;
                bf16x8 v = (bf16x8){0,0,0,0,0,0,0,0};
                if (gm < M) {
                    const float* ap = (const float*)Av + (size_t)gm * K + k0 + kc * 8;
                    float4 a = *(const float4*)ap;
                    float4 b = *(const float4*)(ap + 4);
                    float af_[4] = {a.x, a.y, a.z, a.w}, bf_[4] = {b.x, b.y, b.z, b.w};
                    v = pack8(af_, bf_);
                }
                *(bf16x8*)((char*)Asm + row * 128 + 16 * (kc ^ (row & 7))) = v;
            }
        }
        __syncthreads();

        bf16x8 af[2][2], bfr[2][2];
#pragma unroll
        for (int i = 0; i < 2; ++i) {
#pragma unroll
            for (int kk = 0; kk < 2; ++kk) {
                int arow = wr * 32 + i * 16 + lr;
                af[i][kk]  = *(const bf16x8*)((char*)Asm + arow * 128 + 16 * ((kk * 4 + lg) ^ (arow & 7)));
                int brow = wc * 32 + i * 16 + lr;
                bfr[i][kk] = *(const bf16x8*)((char*)Bsm + brow * 128 + 16 * ((kk * 4 + lg) ^ (brow & 7)));
            }
        }
#pragma unroll
        for (int kk = 0; kk < 2; ++kk)
#pragma unroll
            for (int i = 0; i < 2; ++i)
#pragma unroll
                for (int j = 0; j < 2; ++j)
                    acc[i][j] = __builtin_amdgcn_mfma_f32_16x16x32_bf16(
                        af[i][kk], bfr[j][kk], acc[i][j], 0, 0, 0);
        __syncthreads();
    }

#pragma unroll
    for (int i = 0; i < 2; ++i) {
        int mbase = m0 + wr * 32 + i * 16 + lg * 4;
#pragma unroll
        for (int j = 0; j < 2; ++j) {
            int n = n0 + wc * 32 + j * 16 + lr;
            if (n >= Nreal) continue;
            float bn = bias[n];
#pragma unroll
            for (int r = 0; r < 4; ++r) {
                int m = mbase + r;
                if (m >= M) continue;
                float v = acc[i][j][r] + bn;
                if (RELU) v = fmaxf(v, 0.f);
                if (OUTBF16) ((unsigned short*)Cv)[(size_t)m * Nreal + n] = f2bf(v);
                else         ((float*)Cv)[(size_t)m * Nreal + n] = v;
            }
        }
    }
}

// =====================================================================
// LN over D=256: out = LN(a+b)*g + be; bf16 copy outh.
// =====================================================================
__global__ __launch_bounds__(256) void ln_kernel(
    const float* __restrict__ a, const float* __restrict__ b,
    const float* __restrict__ g, const float* __restrict__ be,
    float* __restrict__ out, unsigned short* __restrict__ outh)
{
    int row  = blockIdx.x * 4 + (threadIdx.x >> 6);
    int lane = threadIdx.x & 63;
    if (row >= MQ) return;

    const float4 va = *(const float4*)(a + (size_t)row * D + lane * 4);
    const float4 vb = *(const float4*)(b + (size_t)row * D + lane * 4);
    float x[4] = { va.x + vb.x, va.y + vb.y, va.z + vb.z, va.w + vb.w };

    float s = x[0] + x[1] + x[2] + x[3];
    float s2 = x[0]*x[0] + x[1]*x[1] + x[2]*x[2] + x[3]*x[3];
#pragma unroll
    for (int o = 32; o >= 1; o >>= 1) {
        s  += __shfl_xor(s,  o);
        s2 += __shfl_xor(s2, o);
    }
    float mean = s * (1.f / D);
    float var  = s2 * (1.f / D) - mean * mean;
    float rinv = rsqrtf(var + 1e-5f);

    float4 vg = *(const float4*)(g  + lane * 4);
    float4 vbe = *(const float4*)(be + lane * 4);
    float4 vo;
    vo.x = (x[0] - mean) * rinv * vg.x + vbe.x;
    vo.y = (x[1] - mean) * rinv * vg.y + vbe.y;
    vo.z = (x[2] - mean) * rinv * vg.z + vbe.z;
    vo.w = (x[3] - mean) * rinv * vg.w + vbe.w;
    *(float4*)(out + (size_t)row * D + lane * 4) = vo;

    ushort4 ho;
    ho.x = f2bf(vo.x); ho.y = f2bf(vo.y); ho.z = f2bf(vo.z); ho.w = f2bf(vo.w);
    *(ushort4*)(outh + (size_t)row * D + lane * 4) = ho;
}

// =====================================================================
// sample kernel, 64 threads/block (1 wave), one query per block.
// Each thread owns 4 elements (u64 = 4 bf16): h = tid>>3, e0 = (tid&7)*4.
// Halves gather transaction count vs r16's u32-pair. Optional inline
// bbox-refinement of the previous layer (the single wave). attn bf16 (u64).
// =====================================================================
template<bool IREF>
__global__ __launch_bounds__(64) void sample_kernel(
    const unsigned short* __restrict__ value, const float* __restrict__ qoa,
    const float* __restrict__ ref_in,
    const unsigned short* __restrict__ t2,
    const float* __restrict__ Wb3, const float* __restrict__ bb3,
    float* __restrict__ ref_out,
    const float* __restrict__ svr,
    unsigned short* __restrict__ attn)
{
    __shared__ float refs[4];

    int nq = blockIdx.x;
    int h  = threadIdx.x >> 3;          // 0..7
    int e0 = (threadIdx.x & 7) * 4;     // 0,4,..,28
    int n  = nq / LQ;

    if (IREF) {
        int lane = threadIdx.x;
        float a0 = 0.f, a1 = 0.f, a2 = 0.f, a3 = 0.f;
        const unsigned short* tp = t2 + (size_t)nq * D;
#pragma unroll
        for (int kk = 0; kk < D / 64; ++kk) {
            int k = lane + kk * 64;
            float tv = bf2f(tp[k]);
            const float4 wrow = *(const float4*)(Wb3 + (size_t)k * 4);
            a0 = fmaf(tv, wrow.x, a0);
            a1 = fmaf(tv, wrow.y, a1);
            a2 = fmaf(tv, wrow.z, a2);
            a3 = fmaf(tv, wrow.w, a3);
        }
#pragma unroll
        for (int o = 32; o >= 1; o >>= 1) {
            a0 += __shfl_xor(a0, o);
            a1 += __shfl_xor(a1, o);
            a2 += __shfl_xor(a2, o);
            a3 += __shfl_xor(a3, o);
        }
        if (lane == 0) {
            float t3[4] = { a0 + bb3[0], a1 + bb3[1], a2 + bb3[2], a3 + bb3[3] };
#pragma unroll
            for (int c = 0; c < 4; ++c) {
                float rp = ref_in[(size_t)nq * 4 + c];
                float xc = fminf(fmaxf(rp, 0.f), 1.f);
                float invsig = logf(fmaxf(xc, 1e-5f) / fmaxf(1.f - xc, 1e-5f));
                float rv = 1.f / (1.f + expf(-(t3[c] + invsig)));
                refs[c] = rv;
                ref_out[(size_t)nq * 4 + c] = rv;
            }
        }
        __syncthreads();
    }

    float vr0 = svr[n * 2 + 0], vr1 = svr[n * 2 + 1];
    float rr0, rr1, rr2, rr3;
    if (IREF) {
        rr0 = refs[0]; rr1 = refs[1]; rr2 = refs[2]; rr3 = refs[3];
    } else {
        rr0 = ref_in[nq * 4 + 0]; rr1 = ref_in[nq * 4 + 1];
        rr2 = ref_in[nq * 4 + 2]; rr3 = ref_in[nq * 4 + 3];
    }
    float r0 = rr0 * vr0;
    float r1 = rr1 * vr1;
    float r2 = rr2 * vr0;
    float r3 = rr3 * vr1;

    const float* qrow = qoa + (size_t)nq * 96;

    float lgt[4];
    float mx = -1e30f;
#pragma unroll
    for (int p = 0; p < 4; ++p) {
        lgt[p] = qrow[64 + h * 4 + p];
        mx = fmaxf(mx, lgt[p]);
    }
    float ssum = 0.f;
#pragma unroll
    for (int p = 0; p < 4; ++p) { lgt[p] = expf(lgt[p] - mx); ssum += lgt[p]; }
    float sinv = 1.f / ssum;

    const unsigned short* vbase = value + (size_t)n * LEN * D + h * DH + e0;
    float acc0 = 0.f, acc1 = 0.f, acc2 = 0.f, acc3 = 0.f;

#pragma unroll
    for (int p = 0; p < NPTS; ++p) {
        float ox = qrow[h * 8 + p * 2 + 0];
        float oy = qrow[h * 8 + p * 2 + 1];
        float lx = r0 + ox * (1.f / NPTS) * r2 * 0.5f;
        float ly = r1 + oy * (1.f / NPTS) * r3 * 0.5f;
        float w  = lgt[p] * sinv;

        float x = lx * W_ - 0.5f;
        float y = ly * H_ - 0.5f;
        x = fminf(fmaxf(x, -1e4f), 1e4f);
        y = fminf(fmaxf(y, -1e4f), 1e4f);
        float x0f = floorf(x), y0f = floorf(y);
        float wx = x - x0f, wy = y - y0f;
        int x0 = (int)x0f, y0 = (int)y0f;

        float cw[4] = { (1.f - wx) * (1.f - wy), wx * (1.f - wy),
                        (1.f - wx) * wy,         wx * wy };
        int xs[4] = { x0, x0 + 1, x0,     x0 + 1 };
        int ys[4] = { y0, y0,     y0 + 1, y0 + 1 };

#pragma unroll
        for (int c = 0; c < 4; ++c) {
            int xi = xs[c], yi = ys[c];
            bool ok = (xi >= 0) & (xi < W_) & (yi >= 0) & (yi < H_);
            if (!ok) continue;
            unsigned long long pv = *(const unsigned long long*)(vbase + (size_t)(yi * W_ + xi) * D);
            float coeff = w * cw[c];
            acc0 = fmaf(coeff, bf2f((unsigned short)(pv & 0xffff)),         acc0);
            acc1 = fmaf(coeff, bf2f((unsigned short)((pv >> 16) & 0xffff)), acc1);
            acc2 = fmaf(coeff, bf2f((unsigned short)((pv >> 32) & 0xffff)), acc2);
            acc3 = fmaf(coeff, bf2f((unsigned short)(pv >> 48)),            acc3);
        }
    }
    unsigned long long outp =
          (unsigned long long)f2bf(acc0)
        | ((unsigned long long)f2bf(acc1) << 16)
        | ((unsigned long long)f2bf(acc2) << 32)
        | ((unsigned long long)f2bf(acc3) << 48);
    *(unsigned long long*)(attn + (size_t)nq * D + h * DH + e0) = outp;
}

// =====================================================================
// bbox final (LAST layer only)
// =====================================================================
__global__ __launch_bounds__(256) void bbox_kernel(
    const unsigned short* __restrict__ t2, const float* __restrict__ Wb3,
    const float* __restrict__ bb3, const float* __restrict__ ref_prev,
    float* __restrict__ ref_out)
{
    int row  = blockIdx.x * 4 + (threadIdx.x >> 6);
    int lane = threadIdx.x & 63;
    if (row >= MQ) return;

    float acc0 = 0.f, acc1 = 0.f, acc2 = 0.f, acc3 = 0.f;
    const unsigned short* tp = t2 + (size_t)row * D;
#pragma unroll
    for (int kk = 0; kk < D / 64; ++kk) {
        int k = lane + kk * 64;
        float tv = bf2f(tp[k]);
        const float4 wrow = *(const float4*)(Wb3 + (size_t)k * 4);
        acc0 = fmaf(tv, wrow.x, acc0);
        acc1 = fmaf(tv, wrow.y, acc1);
        acc2 = fmaf(tv, wrow.z, acc2);
        acc3 = fmaf(tv, wrow.w, acc3);
    }
#pragma unroll
    for (int o = 32; o >= 1; o >>= 1) {
        acc0 += __shfl_xor(acc0, o);
        acc1 += __shfl_xor(acc1, o);
        acc2 += __shfl_xor(acc2, o);
        acc3 += __shfl_xor(acc3, o);
    }
    if (lane == 0) {
        float t3[4] = { acc0 + bb3[0], acc1 + bb3[1], acc2 + bb3[2], acc3 + bb3[3] };
#pragma unroll
        for (int c = 0; c < 4; ++c) {
            float rp = ref_prev[(size_t)row * 4 + c];
            float xc = fminf(fmaxf(rp, 0.f), 1.f);
            float invsig = logf(fmaxf(xc, 1e-5f) / fmaxf(1.f - xc, 1e-5f));
            float sarg = t3[c] + invsig;
            ref_out[(size_t)row * 4 + c] = 1.f / (1.f + expf(-sarg));
        }
    }
}

// =====================================================================
// launcher
// =====================================================================
extern "C" void kernel_launch(void* const* d_in, const int* in_sizes, int n_in,
                              void* d_out, int out_size, void* d_ws, size_t ws_size,
                              hipStream_t stream)
{
    const float* tgt    = (const float*)d_in[0];
    const float* refpts = (const float*)d_in[1];
    const float* src    = (const float*)d_in[2];
    const float* svr    = (const float*)d_in[3];
    const float* qpos   = (const float*)d_in[4];
    const float* Wo     = (const float*)d_in[5];
    const float* bo     = (const float*)d_in[6];
    const float* Wa     = (const float*)d_in[7];
    const float* ba     = (const float*)d_in[8];
    const float* Wv     = (const float*)d_in[9];
    const float* bv     = (const float*)d_in[10];
    const float* Wout   = (const float*)d_in[11];
    const float* bout   = (const float*)d_in[12];
    const float* g1     = (const float*)d_in[13];
    const float* b1     = (const float*)d_in[14];
    const float* Wfc    = (const float*)d_in[15];
    const float* bfc    = (const float*)d_in[16];
    const float* Wproj  = (const float*)d_in[17];
    const float* bproj  = (const float*)d_in[18];
    const float* g2     = (const float*)d_in[19];
    const float* b2     = (const float*)d_in[20];
    const float* Wb1    = (const float*)d_in[21];
    const float* bb1    = (const float*)d_in[22];
    const float* Wb2    = (const float*)d_in[23];
    const float* bb2    = (const float*)d_in[24];
    const float* Wb3    = (const float*)d_in[25];
    const float* bb3    = (const float*)d_in[26];
    const unsigned char* mask = (const unsigned char*)d_in[29];

    float* outp  = (float*)d_out;
    float* inter     = outp;                             // (6, N, LQ, D)
    float* inter_ref = outp + (size_t)NLAYERS * MQ * D;  // (6, N, LQ, 4)

    // workspace carve-up
    char* wsb = (char*)d_ws;
    unsigned short* value    = (unsigned short*)wsb;  wsb += (size_t)MV * D * 2;  // 32 MiB
    unsigned short* src_bf16 = (unsigned short*)wsb;  wsb += (size_t)MV * D * 2;  // 32 MiB
    unsigned short* WvT      = (unsigned short*)wsb;  wsb += (size_t)NLAYERS * D * D * 2;
    unsigned short* WoaT     = (unsigned short*)wsb;  wsb += (size_t)NLAYERS * 128 * D * 2;
    unsigned short* WoutT    = (unsigned short*)wsb;  wsb += (size_t)NLAYERS * D * D * 2;
    unsigned short* WfcT     = (unsigned short*)wsb;  wsb += (size_t)NLAYERS * DFF * D * 2;
    unsigned short* WprojT   = (unsigned short*)wsb;  wsb += (size_t)NLAYERS * D * DFF * 2;
    unsigned short* Wb1T     = (unsigned short*)wsb;  wsb += (size_t)NLAYERS * D * D * 2;
    unsigned short* Wb2T     = (unsigned short*)wsb;  wsb += (size_t)NLAYERS * D * D * 2;
    unsigned short* hmlp     = (unsigned short*)wsb;  wsb += (size_t)MQ * DFF * 2;
    unsigned short* t1b      = (unsigned short*)wsb;  wsb += (size_t)MQ * D * 2;
    unsigned short* t2b      = (unsigned short*)wsb;  wsb += (size_t)MQ * D * 2;
    unsigned short* x1h      = (unsigned short*)wsb;  wsb += (size_t)MQ * D * 2;
    unsigned short* x2h      = (unsigned short*)wsb;  wsb += (size_t)MQ * D * 2;
    unsigned short* attnb    = (unsigned short*)wsb;  wsb += (size_t)MQ * D * 2;
    float* boa   = (float*)wsb;        wsb += (size_t)NLAYERS * 128 * 4;
    float* ws    = (float*)wsb;
    float* qoab  = ws;                 size_t o = (size_t)MQ * 96;
    float* tmpb  = ws + o;             o += (size_t)MQ * D;
    float* x1b   = ws + o;             o += (size_t)MQ * D;

    // ---- one-time conversions (5 dispatches) ----
    cvt_bf16_kernel<<<(MV * D / 8 + 255) / 256, 256, 0, stream>>>(src, src_bf16, MV * D / 8);
    {
        int t = NLAYERS * D * D;
        wt_cvt4_kernel<<<(t + 255) / 256, 256, 0, stream>>>(
            Wv, Wout, Wb1, Wb2, WvT, WoutT, Wb1T, Wb2T);
        t = NLAYERS * DFF * D;
        wt_cvt2_kernel<<<(t + 255) / 256, 256, 0, stream>>>(Wfc, Wproj, WfcT, WprojT);
        t = NLAYERS * 128 * D;
        woat_kernel<<<(t + 255) / 256, 256, 0, stream>>>(Wo, Wa, WoaT);
        bias_concat_kernel<<<(NLAYERS * 128 + 255) / 256, 256, 0, stream>>>(bo, ba, boa);
    }

    // ---- layer-0 prologue: value(0) + qoa(0) ----
    fused_vq_kernel<false><<<VBLK + QBLK, 256, 0, stream>>>(
        src_bf16, WvT, bv, mask, value,
        tgt, qpos, WoaT, boa, qoab,
        nullptr, nullptr, nullptr, nullptr);

    for (int l = 0; l < NLAYERS; ++l) {
        const float* out_prev = (l == 0) ? tgt : inter + (size_t)(l - 1) * MQ * D;
        float* inter_l = inter + (size_t)l * MQ * D;

        // 1) sample (+ inline ref(l-1) refinement for l>=1) -> attn bf16
        if (l == 0) {
            sample_kernel<false><<<MQ, 64, 0, stream>>>(
                value, qoab, refpts, nullptr, nullptr, nullptr, nullptr, svr, attnb);
        } else {
            const float* ref_pp = (l == 1) ? refpts : inter_ref + (size_t)(l - 2) * MQ * 4;
            sample_kernel<true><<<MQ, 64, 0, stream>>>(
                value, qoab, ref_pp, t2b,
                Wb3 + (size_t)(l - 1) * D * 4, bb3 + (size_t)(l - 1) * 4,
                inter_ref + (size_t)(l - 1) * MQ * 4, svr, attnb);
        }

        // 2) attn(bf16) @ Wout + bout  (228 blocks, full async staging)
        gemm_q_mfma<true,false,false><<<dim3(4, MB), 256, 0, stream>>>(
            attnb, WoutT + (size_t)l * D * D, bout + (size_t)l * D, tmpb, MQ, D, D);

        // 3) x1 = LN(out_prev + tmp) -> fp32 + bf16
        ln_kernel<<<MQ / 4, 256, 0, stream>>>(
            out_prev, tmpb, g1 + (size_t)l * D, b1 + (size_t)l * D, x1b, x1h);

        // 4) h = relu(x1h @ Wfc + bfc) -> bf16  (64x64 tile, 912 blocks)
        gemm_q_mfma<true,true,true><<<dim3(DFF / 64, MB), 256, 0, stream>>>(
            x1h, WfcT + (size_t)l * DFF * D, bfc + (size_t)l * DFF, hmlp, MQ, DFF, D);

        // 5) proj: h @ Wproj + bproj  (228 blocks)
        gemm_q_mfma<true,false,false><<<dim3(4, MB), 256, 0, stream>>>(
            hmlp, WprojT + (size_t)l * D * DFF, bproj + (size_t)l * D, tmpb, MQ, D, DFF);

        // 6) x2 = LN(x1 + tmp) -> inter[l] fp32 + bf16
        ln_kernel<<<MQ / 4, 256, 0, stream>>>(
            x1b, tmpb, g2 + (size_t)l * D, b2 + (size_t)l * D, inter_l, x2h);

        // 7) b1(l) overlapped with value(l+1)+qoa(l+1)  [l<5]; plain b1 on last layer
        if (l < NLAYERS - 1) {
            fused_vq_kernel<true><<<VBLK + QBLK + BBLK, 256, 0, stream>>>(
                src_bf16, WvT + (size_t)(l + 1) * D * D, bv + (size_t)(l + 1) * D, mask, value,
                inter_l, qpos, WoaT + (size_t)(l + 1) * 128 * D, boa + (size_t)(l + 1) * 128, qoab,
                x2h, Wb1T + (size_t)l * D * D, bb1 + (size_t)l * D, t1b);
        } else {
            gemm_q_mfma<true,true,true><<<dim3(4, MB), 256, 0, stream>>>(
                x2h, Wb1T + (size_t)l * D * D, bb1 + (size_t)l * D, t1b, MQ, D, D);
        }

        // 8) t2 = relu(t1 @ Wb2 + bb2) -> bf16
        gemm_q_mfma<true,true,true><<<dim3(4, MB), 256, 0, stream>>>(
            t1b, Wb2T + (size_t)l * D * D, bb2 + (size_t)l * D, t2b, MQ, D, D);

        // 9) bbox only for the LAST layer
        if (l == NLAYERS - 1) {
            bbox_kernel<<<MQ / 4, 256, 0, stream>>>(
                t2b, Wb3 + (size_t)l * D * 4, bb3 + (size_t)l * 4,
                inter_ref + (size_t)(l - 1) * MQ * 4, inter_ref + (size_t)l * MQ * 4);
        }
    }
}